// Round 2
// baseline (1557.400 us; speedup 1.0000x reference)
//
#include <hip/hip_runtime.h>
#include <math.h>

#define BV 32
#define LV 196
#define DV 768
#define BT 32
#define LT 64
#define DD 512
#define MV (BV*LV)   /* 6272 */
#define MT (BT*LT)   /* 2048 */
#define TEMPF 20.0f
#define NEGF  -1.0e9f

// Workspace budget: ~32.3M floats ~= 124 MiB (S buffer 51 MiB reused by both
// score GEMMs). All buffers fully written before read each launch (0xAA-safe).

// ---------- helpers ----------
__device__ inline unsigned short f2bf(float f) {
    unsigned int u = __float_as_uint(f);
    unsigned int r = u + 0x7fffu + ((u >> 16) & 1u);
    return (unsigned short)(r >> 16);
}
__device__ inline float blo(unsigned int u) { return __uint_as_float(u << 16); }
__device__ inline float bhi(unsigned int u) { return __uint_as_float(u & 0xffff0000u); }

// ---------- SGEMM NT: C[M,N] = A[M,K] * B[N,K]^T (+bias[N]) ----------
// M % 128 == 0, N % 128 == 0, K % 32 == 0 (all shapes here satisfy this)
#define BM 128
#define BN 128
#define BKK 32

__global__ __launch_bounds__(256)
void sgemm_nt(const float* __restrict__ A, const float* __restrict__ B,
              const float* __restrict__ bias, float* __restrict__ C,
              int M, int N, int K, int hasBias)
{
    __shared__ float As[BKK][BM + 4];
    __shared__ float Bs[BKK][BN + 4];
    const int bm = blockIdx.y * BM;
    const int bn = blockIdx.x * BN;
    const int tid = threadIdx.x;
    const int wave = tid >> 6, lane = tid & 63;
    const int wr = (wave >> 1) * 64, wc = (wave & 1) * 64;
    const int lr = (lane >> 3) * 8, lc = (lane & 7) * 8;

    float acc[8][8];
    #pragma unroll
    for (int i = 0; i < 8; ++i)
        #pragma unroll
        for (int j = 0; j < 8; ++j) acc[i][j] = 0.f;

    for (int k0 = 0; k0 < K; k0 += BKK) {
        #pragma unroll
        for (int i = 0; i < 4; ++i) {
            int idx = tid + 256 * i;       // 0..1023
            int row = idx >> 3;            // 0..127
            int kc  = (idx & 7) << 2;      // 0,4,..,28
            float4 av = *(const float4*)(A + (size_t)(bm + row) * K + k0 + kc);
            As[kc + 0][row] = av.x; As[kc + 1][row] = av.y;
            As[kc + 2][row] = av.z; As[kc + 3][row] = av.w;
            float4 bv = *(const float4*)(B + (size_t)(bn + row) * K + k0 + kc);
            Bs[kc + 0][row] = bv.x; Bs[kc + 1][row] = bv.y;
            Bs[kc + 2][row] = bv.z; Bs[kc + 3][row] = bv.w;
        }
        __syncthreads();
        #pragma unroll 2
        for (int kk = 0; kk < BKK; ++kk) {
            float a[8], b[8];
            *(float4*)&a[0] = *(const float4*)&As[kk][wr + lr];
            *(float4*)&a[4] = *(const float4*)&As[kk][wr + lr + 4];
            *(float4*)&b[0] = *(const float4*)&Bs[kk][wc + lc];
            *(float4*)&b[4] = *(const float4*)&Bs[kk][wc + lc + 4];
            #pragma unroll
            for (int i = 0; i < 8; ++i)
                #pragma unroll
                for (int j = 0; j < 8; ++j)
                    acc[i][j] = fmaf(a[i], b[j], acc[i][j]);
        }
        __syncthreads();
    }

    #pragma unroll
    for (int i = 0; i < 8; ++i) {
        int row = bm + wr + lr + i;
        float* cp = C + (size_t)row * N + bn + wc + lc;
        float o[8];
        #pragma unroll
        for (int j = 0; j < 8; ++j) o[j] = acc[i][j];
        if (hasBias) {
            const float* bp = bias + bn + wc + lc;
            #pragma unroll
            for (int j = 0; j < 8; ++j) o[j] += bp[j];
        }
        *(float4*)cp       = make_float4(o[0], o[1], o[2], o[3]);
        *(float4*)(cp + 4) = make_float4(o[4], o[5], o[6], o[7]);
    }
}

// ---------- row L2 normalize (rows of length 512), 4 rows/block ----------
__global__ __launch_bounds__(256)
void rownorm(const float* __restrict__ in, float* __restrict__ outp, int M)
{
    const int row  = blockIdx.x * 4 + (threadIdx.x >> 6);
    const int lane = threadIdx.x & 63;
    const float* ip = in + (size_t)row * DD + lane * 8;
    float4 x0 = *(const float4*)ip;
    float4 x1 = *(const float4*)(ip + 4);
    float ss = x0.x*x0.x + x0.y*x0.y + x0.z*x0.z + x0.w*x0.w
             + x1.x*x1.x + x1.y*x1.y + x1.z*x1.z + x1.w*x1.w;
    #pragma unroll
    for (int off = 32; off; off >>= 1) ss += __shfl_xor(ss, off, 64);
    const float inv = 1.f / fmaxf(sqrtf(ss), 1e-12f);
    float* op = outp + (size_t)row * DD + lane * 8;
    x0.x *= inv; x0.y *= inv; x0.z *= inv; x0.w *= inv;
    x1.x *= inv; x1.y *= inv; x1.z *= inv; x1.w *= inv;
    *(float4*)op       = x0;
    *(float4*)(op + 4) = x1;
}

// ---------- batched Gram: G[b] = X_b * X_b^T, X_b rows Mg x 512 ----------
__global__ __launch_bounds__(256)
void gram_batched(const float* __restrict__ X, float* __restrict__ G, int Mg)
{
    const int bat = blockIdx.z;
    const int it = blockIdx.y, jt = blockIdx.x;
    const int tid = threadIdx.x;
    const int tx = tid & 15, ty = tid >> 4;
    __shared__ float Xa[32][68];
    __shared__ float Xb[32][68];
    const float* Xbase = X + (size_t)bat * Mg * DD;

    float acc[4][4];
    #pragma unroll
    for (int i = 0; i < 4; ++i)
        #pragma unroll
        for (int j = 0; j < 4; ++j) acc[i][j] = 0.f;

    for (int k0 = 0; k0 < DD; k0 += 32) {
        #pragma unroll
        for (int i = 0; i < 2; ++i) {
            int idx = tid + 256 * i;       // 0..511
            int row = idx >> 3;            // 0..63
            int kc  = (idx & 7) << 2;
            int ra = it * 64 + row; ra = (ra < Mg) ? ra : (Mg - 1);
            int rb = jt * 64 + row; rb = (rb < Mg) ? rb : (Mg - 1);
            float4 av = *(const float4*)(Xbase + (size_t)ra * DD + k0 + kc);
            Xa[kc + 0][row] = av.x; Xa[kc + 1][row] = av.y;
            Xa[kc + 2][row] = av.z; Xa[kc + 3][row] = av.w;
            float4 bv = *(const float4*)(Xbase + (size_t)rb * DD + k0 + kc);
            Xb[kc + 0][row] = bv.x; Xb[kc + 1][row] = bv.y;
            Xb[kc + 2][row] = bv.z; Xb[kc + 3][row] = bv.w;
        }
        __syncthreads();
        #pragma unroll 8
        for (int kk = 0; kk < 32; ++kk) {
            float a[4], b[4];
            *(float4*)a = *(const float4*)&Xa[kk][ty * 4];
            *(float4*)b = *(const float4*)&Xb[kk][tx * 4];
            #pragma unroll
            for (int i = 0; i < 4; ++i)
                #pragma unroll
                for (int j = 0; j < 4; ++j)
                    acc[i][j] = fmaf(a[i], b[j], acc[i][j]);
        }
        __syncthreads();
    }

    #pragma unroll
    for (int i = 0; i < 4; ++i) {
        int row = it * 64 + ty * 4 + i;
        int col = jt * 64 + tx * 4;
        if (row < Mg && col < Mg) {
            float* gp = G + ((size_t)bat * Mg + row) * Mg + col;
            *(float4*)gp = make_float4(acc[i][0], acc[i][1], acc[i][2], acc[i][3]);
        }
    }
}

// ---------- stage 6: att_text side -> a[t][v][512] ----------
// per (t,v): for each of 196 q-rows: softmax over 64 (relu*20, mask->NEG),
// norm via 64x64 Gram (fp32), accumulate w[m] = sum_l p_lm / n_l; a = w . TE_t
__global__ __launch_bounds__(256)
void att_text_stage(const float* __restrict__ S, const float* __restrict__ Gt,
                    const float* __restrict__ TE, const int* __restrict__ mask,
                    float* __restrict__ aacc)
{
    const int t = blockIdx.x, v = blockIdx.y;
    const int tid = threadIdx.x, wave = tid >> 6, lane = tid & 63;
    __shared__ float Gs[64][68];
    __shared__ float pbuf[4][64];
    __shared__ float wacc[4][64];

    {
        const float* gp = Gt + (size_t)t * 64 * 64;
        #pragma unroll
        for (int i = 0; i < 4; ++i) {
            int idx = tid + 256 * i;        // float4 index, 0..1023
            int row = idx >> 4;
            int c4  = (idx & 15) << 2;
            float4 g4 = *(const float4*)(gp + (size_t)idx * 4);
            *(float4*)&Gs[row][c4] = g4;
        }
    }
    wacc[wave][lane] = 0.f;
    const int mk = mask[t * 64 + lane];
    __syncthreads();

    for (int l = wave; l < LV; l += 4) {
        const int r = v * LV + l;
        float s = S[(size_t)r * MT + t * 64 + lane];
        float logit = mk ? NEGF : fmaxf(s, 0.f) * TEMPF;
        float mx = logit;
        #pragma unroll
        for (int off = 32; off; off >>= 1) mx = fmaxf(mx, __shfl_xor(mx, off, 64));
        float p = __expf(logit - mx);
        float sum = p;
        #pragma unroll
        for (int off = 32; off; off >>= 1) sum += __shfl_xor(sum, off, 64);
        p /= sum;
        pbuf[wave][lane] = p;
        float u = 0.f;
        #pragma unroll
        for (int mb = 0; mb < 64; mb += 4) {
            float4 p4 = *(const float4*)&pbuf[wave][mb];
            float4 g4 = *(const float4*)&Gs[lane][mb];
            u = fmaf(p4.x, g4.x, u); u = fmaf(p4.y, g4.y, u);
            u = fmaf(p4.z, g4.z, u); u = fmaf(p4.w, g4.w, u);
        }
        float nsq = p * u;
        #pragma unroll
        for (int off = 32; off; off >>= 1) nsq += __shfl_xor(nsq, off, 64);
        float inv = 1.f / fmaxf(sqrtf(fmaxf(nsq, 0.f)), 1e-12f);
        wacc[wave][lane] += p * inv;
    }
    __syncthreads();
    if (tid < 64)
        wacc[0][tid] = wacc[0][tid] + wacc[1][tid] + wacc[2][tid] + wacc[3][tid];
    __syncthreads();

    const int d = tid * 2;
    float a0 = 0.f, a1 = 0.f;
    const float* tb = TE + (size_t)(t * 64) * DD + d;
    for (int m = 0; m < 64; ++m) {
        float wm = wacc[0][m];
        float2 te = *(const float2*)(tb + (size_t)m * DD);
        a0 = fmaf(wm, te.x, a0);
        a1 = fmaf(wm, te.y, a1);
    }
    *(float2*)(aacc + ((size_t)t * 32 + v) * DD + d) = make_float2(a0, a1);
}

// ---------- stage 8: att_vis side -> b[v][t][512] ----------
// 196x196 Gram kept as bf16 off-diagonal in LDS + fp32 diagonal (the
// diagonal dominates p^T G p for peaked softmax; fp32 there kills the
// bf16 rounding risk against the 1.06e-3 absmax threshold).
#define G_LD 200
__global__ __launch_bounds__(512)
void att_vis_stage(const float* __restrict__ S2, const float* __restrict__ Gv,
                   const float* __restrict__ VE, const int* __restrict__ mask,
                   float* __restrict__ bacc)
{
    const int t = blockIdx.x, v = blockIdx.y;
    const int tid = threadIdx.x;
    const int wave = tid >> 6, lane = tid & 63;
    __shared__ unsigned short Gs[196][G_LD];
    __shared__ float diagF[196];
    __shared__ float pbuf[8][G_LD];
    __shared__ float wacc[8][G_LD];

    const float* gp = Gv + (size_t)v * 196 * 196;
    for (int idx = tid; idx < 196 * 49; idx += 512) {
        float4 g4 = *(const float4*)(gp + (size_t)idx * 4);
        int row = idx / 49;
        int col = (idx - row * 49) * 4;
        Gs[row][col + 0] = f2bf(g4.x);
        Gs[row][col + 1] = f2bf(g4.y);
        Gs[row][col + 2] = f2bf(g4.z);
        Gs[row][col + 3] = f2bf(g4.w);
    }
    for (int idx = tid; idx < 196; idx += 512) {
        Gs[idx][196] = 0; Gs[idx][197] = 0; Gs[idx][198] = 0; Gs[idx][199] = 0;
    }
    __syncthreads();
    // fp32 diagonal; zero the bf16 diagonal (compensated in nsq below)
    for (int idx = tid; idx < 196; idx += 512) {
        diagF[idx] = gp[(size_t)idx * 197];
        Gs[idx][idx] = 0;
    }
    for (int j = lane; j < G_LD; j += 64) wacc[wave][j] = 0.f;
    if (lane < 4) pbuf[wave][196 + lane] = 0.f;
    __syncthreads();

    const int r3 = (lane < 4) ? (lane + 192) : lane;  // dummy row for lanes>=4 (p3=0)
    for (int m = wave; m < 64; m += 8) {
        const int rrow = t * 64 + m;
        const int mk = mask[rrow];
        const float* srow = S2 + (size_t)rrow * MV + v * 196;
        float l0 = fmaxf(srow[lane], 0.f) * TEMPF;
        float l1 = fmaxf(srow[lane + 64], 0.f) * TEMPF;
        float l2 = fmaxf(srow[lane + 128], 0.f) * TEMPF;
        float l3 = -3.0e38f;
        if (lane < 4) l3 = fmaxf(srow[lane + 192], 0.f) * TEMPF;
        float mx = fmaxf(fmaxf(l0, l1), fmaxf(l2, l3));
        #pragma unroll
        for (int off = 32; off; off >>= 1) mx = fmaxf(mx, __shfl_xor(mx, off, 64));
        float p0 = __expf(l0 - mx), p1 = __expf(l1 - mx), p2 = __expf(l2 - mx);
        float p3 = (lane < 4) ? __expf(l3 - mx) : 0.f;
        float sum = p0 + p1 + p2 + p3;
        #pragma unroll
        for (int off = 32; off; off >>= 1) sum += __shfl_xor(sum, off, 64);
        float rs = 1.f / sum;
        p0 *= rs; p1 *= rs; p2 *= rs; p3 *= rs;
        pbuf[wave][lane] = p0; pbuf[wave][lane + 64] = p1; pbuf[wave][lane + 128] = p2;
        if (lane < 4) pbuf[wave][lane + 192] = p3;

        float u0 = 0.f, u1 = 0.f, u2 = 0.f, u3 = 0.f;
        for (int mb = 0; mb < G_LD; mb += 8) {
            float4 pa = *(const float4*)&pbuf[wave][mb];
            float4 pb = *(const float4*)&pbuf[wave][mb + 4];
            uint4 g0 = *(const uint4*)&Gs[lane][mb];
            uint4 g1 = *(const uint4*)&Gs[lane + 64][mb];
            uint4 g2 = *(const uint4*)&Gs[lane + 128][mb];
            uint4 g3 = *(const uint4*)&Gs[r3][mb];
            u0 += pa.x*blo(g0.x) + pa.y*bhi(g0.x) + pa.z*blo(g0.y) + pa.w*bhi(g0.y)
                + pb.x*blo(g0.z) + pb.y*bhi(g0.z) + pb.z*blo(g0.w) + pb.w*bhi(g0.w);
            u1 += pa.x*blo(g1.x) + pa.y*bhi(g1.x) + pa.z*blo(g1.y) + pa.w*bhi(g1.y)
                + pb.x*blo(g1.z) + pb.y*bhi(g1.z) + pb.z*blo(g1.w) + pb.w*bhi(g1.w);
            u2 += pa.x*blo(g2.x) + pa.y*bhi(g2.x) + pa.z*blo(g2.y) + pa.w*bhi(g2.y)
                + pb.x*blo(g2.z) + pb.y*bhi(g2.z) + pb.z*blo(g2.w) + pb.w*bhi(g2.w);
            u3 += pa.x*blo(g3.x) + pa.y*bhi(g3.x) + pa.z*blo(g3.y) + pa.w*bhi(g3.y)
                + pb.x*blo(g3.z) + pb.y*bhi(g3.z) + pb.z*blo(g3.w) + pb.w*bhi(g3.w);
        }
        float nsq = p0 * (u0 + diagF[lane] * p0)
                  + p1 * (u1 + diagF[lane + 64] * p1)
                  + p2 * (u2 + diagF[lane + 128] * p2);
        if (lane < 4) nsq += p3 * (u3 + diagF[lane + 192] * p3);
        #pragma unroll
        for (int off = 32; off; off >>= 1) nsq += __shfl_xor(nsq, off, 64);
        float inv = 1.f / fmaxf(sqrtf(fmaxf(nsq, 0.f)), 1e-12f);
        if (mk) inv = 0.f;   // masked text position -> excluded from b
        wacc[wave][lane]       += p0 * inv;
        wacc[wave][lane + 64]  += p1 * inv;
        wacc[wave][lane + 128] += p2 * inv;
        if (lane < 4) wacc[wave][lane + 192] += p3 * inv;
    }
    __syncthreads();
    if (tid < 196) {
        float ws = 0.f;
        #pragma unroll
        for (int w = 0; w < 8; ++w) ws += wacc[w][tid];
        wacc[0][tid] = ws;
    }
    __syncthreads();

    float acc0 = 0.f, acc1 = 0.f;
    const float* vb = VE + (size_t)v * 196 * DD + tid;
    for (int j = 0; j < 196; j += 2) {
        acc0 = fmaf(wacc[0][j],     vb[(size_t)j * DD],       acc0);
        acc1 = fmaf(wacc[0][j + 1], vb[(size_t)(j + 1) * DD], acc1);
    }
    bacc[((size_t)v * 32 + t) * DD + tid] = acc0 + acc1;
}

// ---------- final: out[t,v] = dot(a[t,v,:], b[v,t,:]) / (196*64) ----------
__global__ __launch_bounds__(64)
void final_dot(const float* __restrict__ aacc, const float* __restrict__ bacc,
               float* __restrict__ out)
{
    const int t = blockIdx.x, v = blockIdx.y;
    const int lane = threadIdx.x;
    const float* ap = aacc + ((size_t)t * 32 + v) * DD + lane * 8;
    const float* bp = bacc + ((size_t)v * 32 + t) * DD + lane * 8;
    float4 a0 = *(const float4*)ap,       a1 = *(const float4*)(ap + 4);
    float4 b0 = *(const float4*)bp,       b1 = *(const float4*)(bp + 4);
    float acc = a0.x*b0.x + a0.y*b0.y + a0.z*b0.z + a0.w*b0.w
              + a1.x*b1.x + a1.y*b1.y + a1.z*b1.z + a1.w*b1.w;
    #pragma unroll
    for (int off = 32; off; off >>= 1) acc += __shfl_xor(acc, off, 64);
    if (lane == 0) out[(size_t)t * 32 + v] = acc * (1.f / 12544.f);
}

// ---------- launcher ----------
extern "C" void kernel_launch(void* const* d_in, const int* in_sizes, int n_in,
                              void* d_out, int out_size, void* d_ws, size_t ws_size,
                              hipStream_t stream)
{
    const float* VF   = (const float*)d_in[0];
    const float* TF   = (const float*)d_in[1];
    const int*   mask = (const int*)  d_in[2];
    const float* Wv   = (const float*)d_in[3];
    const float* bv   = (const float*)d_in[4];
    const float* Wt   = (const float*)d_in[5];
    const float* bt   = (const float*)d_in[6];
    const float* Wq   = (const float*)d_in[7];
    const float* Wk   = (const float*)d_in[8];
    float* out = (float*)d_out;

    float* ws = (float*)d_ws;
    size_t off = 0;
    float* VE  = ws + off; off += (size_t)MV * DD;
    float* VN  = ws + off; off += (size_t)MV * DD;
    float* TE  = ws + off; off += (size_t)MT * DD;
    float* TN  = ws + off; off += (size_t)MT * DD;
    float* Qv  = ws + off; off += (size_t)MV * DD;
    float* Kv  = ws + off; off += (size_t)MV * DD;
    float* Qt  = ws + off; off += (size_t)MT * DD;
    float* Kt  = ws + off; off += (size_t)MT * DD;
    float* S   = ws + off; off += (size_t)MV * MT;    // shared by S1 and S2
    float* Gt  = ws + off; off += (size_t)32 * 64 * 64;
    float* Gv  = ws + off; off += (size_t)32 * 196 * 196;
    float* Aac = ws + off; off += (size_t)32 * 32 * DD;
    float* Bac = ws + off; off += (size_t)32 * 32 * DD;

    const dim3 blk(256);

    // embeds (+bias)
    sgemm_nt<<<dim3(DD / BN, MV / BM), blk, 0, stream>>>(VF, Wv, bv, VE, MV, DD, DV, 1);
    sgemm_nt<<<dim3(DD / BN, MT / BM), blk, 0, stream>>>(TF, Wt, bt, TE, MT, DD, DV, 1);
    rownorm<<<MV / 4, 256, 0, stream>>>(VE, VN, MV);
    rownorm<<<MT / 4, 256, 0, stream>>>(TE, TN, MT);

    // projections + normalize (in place)
    sgemm_nt<<<dim3(DD / BN, MV / BM), blk, 0, stream>>>(VN, Wq, nullptr, Qv, MV, DD, DD, 0);
    sgemm_nt<<<dim3(DD / BN, MV / BM), blk, 0, stream>>>(VN, Wk, nullptr, Kv, MV, DD, DD, 0);
    sgemm_nt<<<dim3(DD / BN, MT / BM), blk, 0, stream>>>(TN, Wq, nullptr, Qt, MT, DD, DD, 0);
    sgemm_nt<<<dim3(DD / BN, MT / BM), blk, 0, stream>>>(TN, Wk, nullptr, Kt, MT, DD, DD, 0);
    rownorm<<<MV / 4, 256, 0, stream>>>(Qv, Qv, MV);
    rownorm<<<MV / 4, 256, 0, stream>>>(Kv, Kv, MV);
    rownorm<<<MT / 4, 256, 0, stream>>>(Qt, Qt, MT);
    rownorm<<<MT / 4, 256, 0, stream>>>(Kt, Kt, MT);

    // Grams (for Gram-trick row norms)
    gram_batched<<<dim3(1, 1, 32), blk, 0, stream>>>(TE, Gt, 64);
    gram_batched<<<dim3(4, 4, 32), blk, 0, stream>>>(VE, Gv, 196);

    // text-attending direction: S1 = Qv * Kt^T, then fused softmax/norm/reduce
    sgemm_nt<<<dim3(MT / BN, MV / BM), blk, 0, stream>>>(Qv, Kt, nullptr, S, MV, MT, DD, 0);
    att_text_stage<<<dim3(32, 32), 256, 0, stream>>>(S, Gt, TE, mask, Aac);

    // vis-attending direction: S2 = Qt * Kv^T (reuses S), then fused stage
    sgemm_nt<<<dim3(MV / BN, MT / BM), blk, 0, stream>>>(Qt, Kv, nullptr, S, MT, MV, DD, 0);
    att_vis_stage<<<dim3(32, 32), 512, 0, stream>>>(S, Gv, VE, mask, Bac);

    final_dot<<<dim3(32, 32), 64, 0, stream>>>(Aac, Bac, out);
}

// Round 4
// 853.119 us; speedup vs baseline: 1.8255x; 1.8255x over previous
//
#include <hip/hip_runtime.h>
#include <math.h>

#define BV 32
#define LV 196
#define DV 768
#define BT 32
#define LT 64
#define DD 512
#define MV (BV*LV)   /* 6272 */
#define MT (BT*LT)   /* 2048 */
#define TEMPF 20.0f
#define NEGF  -1.0e9f

typedef unsigned short u16;
typedef unsigned int   u32;
typedef short bf16x8 __attribute__((ext_vector_type(8)));
typedef float f32x4  __attribute__((ext_vector_type(4)));

// ---------- helpers ----------
__device__ __forceinline__ u16 f2bf(float f) {
    u32 u = __float_as_uint(f);
    u32 r = u + 0x7fffu + ((u >> 16) & 1u);
    return (u16)(r >> 16);
}
__device__ __forceinline__ float bf2f(u16 h) { return __uint_as_float(((u32)h) << 16); }
__device__ __forceinline__ float blo(u32 u) { return __uint_as_float(u << 16); }
__device__ __forceinline__ float bhi(u32 u) { return __uint_as_float(u & 0xffff0000u); }

// Tiled-swizzled bf16 layout: matrix [M][K2=2K] stored as 128x64 tiles.
// Tile (rowBlk,kBlk) occupies 8192 ushorts; inside, element (row, ke) sits at
// byte row*128 + (((ke>>3) ^ (row&7))<<4) + (ke&7)*2  — i.e. the LDS image the
// GEMM wants (linear global_load_lds dest + XOR-swizzled ds_read, m173/m201).
__device__ __forceinline__ size_t tiled_chunk_off(int m, int kk, int KB2) {
    // kk multiple of 8; returns ushort index of the 16B chunk
    int rowBlk = m >> 7, row = m & 127;
    int kBlk = kk >> 6, ke = kk & 63;
    return ((size_t)(rowBlk * KB2 + kBlk) << 13) + row * 64 + ((((ke >> 3) ^ (row & 7)) << 4) >> 1);
}

// ---------- conv: X fp32 [M][K] -> X2 bf16 tiled [hi | lo] (K2 = 2K) ----------
__global__ __launch_bounds__(256)
void conv_split(const float* __restrict__ X, u16* __restrict__ X2, int M, int K)
{
    int gid = blockIdx.x * 256 + threadIdx.x;
    int perRow = K >> 3;
    if (gid >= M * perRow) return;
    int m = gid / perRow, k8 = (gid - m * perRow) << 3;
    const float* xp = X + (size_t)m * K + k8;
    float x[8];
    *(float4*)&x[0] = *(const float4*)xp;
    *(float4*)&x[4] = *(const float4*)(xp + 4);
    union { u16 h[8]; uint4 v; } hi, lo;
    #pragma unroll
    for (int e = 0; e < 8; ++e) {
        hi.h[e] = f2bf(x[e]);
        lo.h[e] = f2bf(x[e] - bf2f(hi.h[e]));
    }
    int KB2 = K >> 5;
    *(uint4*)&X2[tiled_chunk_off(m, k8, KB2)]     = hi.v;
    *(uint4*)&X2[tiled_chunk_off(m, K + k8, KB2)] = lo.v;
}

// ---------- fused rownorm + split conv (rows of 512) ----------
__global__ __launch_bounds__(256)
void rownorm_conv(const float* __restrict__ X, u16* __restrict__ X2, int M)
{
    const int row  = blockIdx.x * 4 + (threadIdx.x >> 6);
    const int lane = threadIdx.x & 63;
    const float* ip = X + (size_t)row * DD + lane * 8;
    float x[8];
    *(float4*)&x[0] = *(const float4*)ip;
    *(float4*)&x[4] = *(const float4*)(ip + 4);
    float ss = 0.f;
    #pragma unroll
    for (int e = 0; e < 8; ++e) ss += x[e] * x[e];
    #pragma unroll
    for (int off = 32; off; off >>= 1) ss += __shfl_xor(ss, off, 64);
    const float inv = 1.f / fmaxf(sqrtf(ss), 1e-12f);
    union { u16 h[8]; uint4 v; } hi, lo;
    #pragma unroll
    for (int e = 0; e < 8; ++e) {
        float xv = x[e] * inv;
        hi.h[e] = f2bf(xv);
        lo.h[e] = f2bf(xv - bf2f(hi.h[e]));
    }
    const int k8 = lane * 8, KB2 = 16;  // K=512
    *(uint4*)&X2[tiled_chunk_off(row, k8, KB2)]       = hi.v;
    *(uint4*)&X2[tiled_chunk_off(row, DD + k8, KB2)]  = lo.v;
}

// ---------- split-bf16 MFMA GEMM NT: C[M,N] = A*B^T (+bias) ----------
// A2/B2 in tiled-swizzled [hi|lo] form. 3 passes folded into one k-loop:
// t<KB: Ah*Bh ; KB<=t<2KB: Ah*Bl ; t>=2KB: Al*Bh  (Al*Bl dropped, ~1e-5 rel)
__device__ __forceinline__ void gload16(const u16* g, u16* l) {
    __builtin_amdgcn_global_load_lds((const __attribute__((address_space(1))) u32*)g,
                                     (__attribute__((address_space(3))) u32*)l, 16, 0, 0);
}

__global__ __launch_bounds__(256, 2)
void gemm_split_nt(const u16* __restrict__ A2, const u16* __restrict__ B2,
                   const float* __restrict__ bias, float* __restrict__ C,
                   int M, int N, int K, int hasBias)
{
    const int KB  = K >> 6;       // 64-col tiles per half
    const int KB2 = KB * 2;
    const int bm = blockIdx.y, bn = blockIdx.x;
    const int tid = threadIdx.x;
    const int w = tid >> 6, lane = tid & 63;
    const int wr = (w >> 1) << 6, wc = (w & 1) << 6;
    const int fr = lane & 15, fq = lane >> 4;

    __shared__ u16 As[2][8192];
    __shared__ u16 Bs[2][8192];

    f32x4 acc[4][4];
    #pragma unroll
    for (int i = 0; i < 4; ++i)
        #pragma unroll
        for (int j = 0; j < 4; ++j) acc[i][j] = (f32x4){0.f, 0.f, 0.f, 0.f};

    // ds_read offsets (ushort units): row&7 == fr&7 for all frags
    const int swz = (fr & 7) << 4;
    const int aoff0 = ((wr + fr) << 7) >> 1;   // row*128 bytes -> ushorts
    const int boff0 = ((wc + fr) << 7) >> 1;
    const int k0 = ((fq << 4) ^ swz) >> 1;          // ks=0
    const int k1 = ((64 + (fq << 4)) ^ swz) >> 1;   // ks=1

    const int c4 = w * 4;                       // 4 chunks per wave
    const int laneOff = c4 * 512 + lane * 8;    // ushort offset of this lane's 16B

    const int T = 3 * KB;
    int cur = 0;

    // prologue: stage tile 0 (ab=0, bb=0)
    {
        const u16* ag = A2 + (((size_t)(bm * KB2)) << 13) + laneOff;
        const u16* bg = B2 + (((size_t)(bn * KB2)) << 13) + laneOff;
        #pragma unroll
        for (int i = 0; i < 4; ++i) {
            gload16(ag + i * 512, &As[0][(c4 + i) * 512]);
            gload16(bg + i * 512, &Bs[0][(c4 + i) * 512]);
        }
    }
    __syncthreads();

    for (int t = 0; t < T; ++t) {
        if (t + 1 < T) {
            int tn = t + 1, ab, bb;
            if (tn < KB)           { ab = tn;          bb = tn; }
            else if (tn < 2 * KB)  { ab = tn - KB;     bb = tn; }
            else                   { ab = tn - KB;     bb = tn - 2 * KB; }
            const u16* ag = A2 + (((size_t)(bm * KB2 + ab)) << 13) + laneOff;
            const u16* bg = B2 + (((size_t)(bn * KB2 + bb)) << 13) + laneOff;
            int nb = cur ^ 1;
            #pragma unroll
            for (int i = 0; i < 4; ++i) {
                gload16(ag + i * 512, &As[nb][(c4 + i) * 512]);
                gload16(bg + i * 512, &Bs[nb][(c4 + i) * 512]);
            }
        }
        // compute current tile: 2 k-steps x 16 MFMA
        #pragma unroll
        for (int ks = 0; ks < 2; ++ks) {
            const int kk = ks ? k1 : k0;
            bf16x8 af[4], bfv[4];
            #pragma unroll
            for (int mi = 0; mi < 4; ++mi)
                af[mi] = *(const bf16x8*)&As[cur][aoff0 + mi * 1024 + kk];
            #pragma unroll
            for (int ni = 0; ni < 4; ++ni)
                bfv[ni] = *(const bf16x8*)&Bs[cur][boff0 + ni * 1024 + kk];
            #pragma unroll
            for (int mi = 0; mi < 4; ++mi)
                #pragma unroll
                for (int ni = 0; ni < 4; ++ni)
                    acc[mi][ni] = __builtin_amdgcn_mfma_f32_16x16x32_bf16(
                        af[mi], bfv[ni], acc[mi][ni], 0, 0, 0);
        }
        __syncthreads();   // drains stage loads + guards LDS reuse
        cur ^= 1;
    }

    // epilogue: C[row][col], col = fr, row = fq*4+j (m89-verified mapping)
    #pragma unroll
    for (int ni = 0; ni < 4; ++ni) {
        const int col = (bn << 7) + wc + ni * 16 + fr;
        const float badd = hasBias ? bias[col] : 0.f;
        #pragma unroll
        for (int mi = 0; mi < 4; ++mi) {
            #pragma unroll
            for (int j = 0; j < 4; ++j) {
                const int row = (bm << 7) + wr + mi * 16 + fq * 4 + j;
                C[(size_t)row * N + col] = acc[mi][ni][j] + badd;
            }
        }
    }
}

// ---------- batched Gram: G[b] = X_b * X_b^T, X_b rows Mg x 512 (fp32) ----------
__global__ __launch_bounds__(256)
void gram_batched(const float* __restrict__ X, float* __restrict__ G, int Mg)
{
    const int bat = blockIdx.z;
    const int it = blockIdx.y, jt = blockIdx.x;
    const int tid = threadIdx.x;
    const int tx = tid & 15, ty = tid >> 4;
    __shared__ float Xa[32][68];
    __shared__ float Xb[32][68];
    const float* Xbase = X + (size_t)bat * Mg * DD;

    float acc[4][4];
    #pragma unroll
    for (int i = 0; i < 4; ++i)
        #pragma unroll
        for (int j = 0; j < 4; ++j) acc[i][j] = 0.f;

    for (int k0 = 0; k0 < DD; k0 += 32) {
        #pragma unroll
        for (int i = 0; i < 2; ++i) {
            int idx = tid + 256 * i;
            int row = idx >> 3;
            int kc  = (idx & 7) << 2;
            int ra = it * 64 + row; ra = (ra < Mg) ? ra : (Mg - 1);
            int rb = jt * 64 + row; rb = (rb < Mg) ? rb : (Mg - 1);
            float4 av = *(const float4*)(Xbase + (size_t)ra * DD + k0 + kc);
            Xa[kc + 0][row] = av.x; Xa[kc + 1][row] = av.y;
            Xa[kc + 2][row] = av.z; Xa[kc + 3][row] = av.w;
            float4 bv = *(const float4*)(Xbase + (size_t)rb * DD + k0 + kc);
            Xb[kc + 0][row] = bv.x; Xb[kc + 1][row] = bv.y;
            Xb[kc + 2][row] = bv.z; Xb[kc + 3][row] = bv.w;
        }
        __syncthreads();
        #pragma unroll 8
        for (int kk = 0; kk < 32; ++kk) {
            float a[4], b[4];
            *(float4*)a = *(const float4*)&Xa[kk][ty * 4];
            *(float4*)b = *(const float4*)&Xb[kk][tx * 4];
            #pragma unroll
            for (int i = 0; i < 4; ++i)
                #pragma unroll
                for (int j = 0; j < 4; ++j)
                    acc[i][j] = fmaf(a[i], b[j], acc[i][j]);
        }
        __syncthreads();
    }

    #pragma unroll
    for (int i = 0; i < 4; ++i) {
        int row = it * 64 + ty * 4 + i;
        int col = jt * 64 + tx * 4;
        if (row < Mg && col < Mg) {
            float* gp = G + ((size_t)bat * Mg + row) * Mg + col;
            *(float4*)gp = make_float4(acc[i][0], acc[i][1], acc[i][2], acc[i][3]);
        }
    }
}

// ---------- att_text: softmax(64) + Gram-norm + weight-reduce -> a[t][v][512] ----------
__global__ __launch_bounds__(256)
void att_text_stage(const float* __restrict__ S, const float* __restrict__ Gt,
                    const float* __restrict__ TE, const int* __restrict__ mask,
                    float* __restrict__ aacc)
{
    const int t = blockIdx.x, v = blockIdx.y;
    const int tid = threadIdx.x, wave = tid >> 6, lane = tid & 63;
    __shared__ float Gs[64][68];
    __shared__ float pbuf[4][64];
    __shared__ float wacc[4][64];

    {
        const float* gp = Gt + (size_t)t * 64 * 64;
        #pragma unroll
        for (int i = 0; i < 4; ++i) {
            int idx = tid + 256 * i;
            int row = idx >> 4;
            int c4  = (idx & 15) << 2;
            float4 g4 = *(const float4*)(gp + (size_t)idx * 4);
            *(float4*)&Gs[row][c4] = g4;
        }
    }
    wacc[wave][lane] = 0.f;
    const int mk = mask[t * 64 + lane];
    __syncthreads();

    for (int l = wave; l < LV; l += 4) {
        const int r = v * LV + l;
        float s = S[(size_t)r * MT + t * 64 + lane];
        float logit = mk ? NEGF : fmaxf(s, 0.f) * TEMPF;
        float mx = logit;
        #pragma unroll
        for (int off = 32; off; off >>= 1) mx = fmaxf(mx, __shfl_xor(mx, off, 64));
        float p = __expf(logit - mx);
        float sum = p;
        #pragma unroll
        for (int off = 32; off; off >>= 1) sum += __shfl_xor(sum, off, 64);
        p /= sum;
        pbuf[wave][lane] = p;
        float u = 0.f;
        #pragma unroll
        for (int mb = 0; mb < 64; mb += 4) {
            float4 p4 = *(const float4*)&pbuf[wave][mb];
            float4 g4 = *(const float4*)&Gs[lane][mb];
            u = fmaf(p4.x, g4.x, u); u = fmaf(p4.y, g4.y, u);
            u = fmaf(p4.z, g4.z, u); u = fmaf(p4.w, g4.w, u);
        }
        float nsq = p * u;
        #pragma unroll
        for (int off = 32; off; off >>= 1) nsq += __shfl_xor(nsq, off, 64);
        float inv = 1.f / fmaxf(sqrtf(fmaxf(nsq, 0.f)), 1e-12f);
        wacc[wave][lane] += p * inv;
    }
    __syncthreads();
    if (tid < 64)
        wacc[0][tid] = wacc[0][tid] + wacc[1][tid] + wacc[2][tid] + wacc[3][tid];
    __syncthreads();

    const int d = tid * 2;
    float a0 = 0.f, a1 = 0.f;
    const float* tb = TE + (size_t)(t * 64) * DD + d;
    for (int m = 0; m < 64; ++m) {
        float wm = wacc[0][m];
        float2 te = *(const float2*)(tb + (size_t)m * DD);
        a0 = fmaf(wm, te.x, a0);
        a1 = fmaf(wm, te.y, a1);
    }
    *(float2*)(aacc + ((size_t)t * 32 + v) * DD + d) = make_float2(a0, a1);
}

// ---------- att_vis: softmax(196) + Gram-norm (bf16 offdiag + fp32 diag) ----------
#define G_LD 200
__global__ __launch_bounds__(512)
void att_vis_stage(const float* __restrict__ S2, const float* __restrict__ Gv,
                   const float* __restrict__ VE, const int* __restrict__ mask,
                   float* __restrict__ bacc)
{
    const int t = blockIdx.x, v = blockIdx.y;
    const int tid = threadIdx.x;
    const int wave = tid >> 6, lane = tid & 63;
    __shared__ u16 Gs[196][G_LD];
    __shared__ float diagF[196];
    __shared__ float pbuf[8][G_LD];
    __shared__ float wacc[8][G_LD];

    const float* gp = Gv + (size_t)v * 196 * 196;
    for (int idx = tid; idx < 196 * 49; idx += 512) {
        float4 g4 = *(const float4*)(gp + (size_t)idx * 4);
        int row = idx / 49;
        int col = (idx - row * 49) * 4;
        Gs[row][col + 0] = f2bf(g4.x);
        Gs[row][col + 1] = f2bf(g4.y);
        Gs[row][col + 2] = f2bf(g4.z);
        Gs[row][col + 3] = f2bf(g4.w);
    }
    for (int idx = tid; idx < 196; idx += 512) {
        Gs[idx][196] = 0; Gs[idx][197] = 0; Gs[idx][198] = 0; Gs[idx][199] = 0;
    }
    __syncthreads();
    for (int idx = tid; idx < 196; idx += 512) {
        diagF[idx] = gp[(size_t)idx * 197];
        Gs[idx][idx] = 0;
    }
    for (int j = lane; j < G_LD; j += 64) wacc[wave][j] = 0.f;
    if (lane < 4) pbuf[wave][196 + lane] = 0.f;
    __syncthreads();

    const int r3 = (lane < 4) ? (lane + 192) : lane;
    for (int m = wave; m < 64; m += 8) {
        const int rrow = t * 64 + m;
        const int mk = mask[rrow];
        const float* srow = S2 + (size_t)rrow * MV + v * 196;
        float l0 = fmaxf(srow[lane], 0.f) * TEMPF;
        float l1 = fmaxf(srow[lane + 64], 0.f) * TEMPF;
        float l2 = fmaxf(srow[lane + 128], 0.f) * TEMPF;
        float l3 = -3.0e38f;
        if (lane < 4) l3 = fmaxf(srow[lane + 192], 0.f) * TEMPF;
        float mx = fmaxf(fmaxf(l0, l1), fmaxf(l2, l3));
        #pragma unroll
        for (int off = 32; off; off >>= 1) mx = fmaxf(mx, __shfl_xor(mx, off, 64));
        float p0 = __expf(l0 - mx), p1 = __expf(l1 - mx), p2 = __expf(l2 - mx);
        float p3 = (lane < 4) ? __expf(l3 - mx) : 0.f;
        float sum = p0 + p1 + p2 + p3;
        #pragma unroll
        for (int off = 32; off; off >>= 1) sum += __shfl_xor(sum, off, 64);
        float rs = 1.f / sum;
        p0 *= rs; p1 *= rs; p2 *= rs; p3 *= rs;
        pbuf[wave][lane] = p0; pbuf[wave][lane + 64] = p1; pbuf[wave][lane + 128] = p2;
        if (lane < 4) pbuf[wave][lane + 192] = p3;

        float u0 = 0.f, u1 = 0.f, u2 = 0.f, u3 = 0.f;
        for (int mb = 0; mb < G_LD; mb += 8) {
            float4 pa = *(const float4*)&pbuf[wave][mb];
            float4 pb = *(const float4*)&pbuf[wave][mb + 4];
            uint4 g0 = *(const uint4*)&Gs[lane][mb];
            uint4 g1 = *(const uint4*)&Gs[lane + 64][mb];
            uint4 g2 = *(const uint4*)&Gs[lane + 128][mb];
            uint4 g3 = *(const uint4*)&Gs[r3][mb];
            u0 += pa.x*blo(g0.x) + pa.y*bhi(g0.x) + pa.z*blo(g0.y) + pa.w*bhi(g0.y)
                + pb.x*blo(g0.z) + pb.y*bhi(g0.z) + pb.z*blo(g0.w) + pb.w*bhi(g0.w);
            u1 += pa.x*blo(g1.x) + pa.y*bhi(g1.x) + pa.z*blo(g1.y) + pa.w*bhi(g1.y)
                + pb.x*blo(g1.z) + pb.y*bhi(g1.z) + pb.z*blo(g1.w) + pb.w*bhi(g1.w);
            u2 += pa.x*blo(g2.x) + pa.y*bhi(g2.x) + pa.z*blo(g2.y) + pa.w*bhi(g2.y)
                + pb.x*blo(g2.z) + pb.y*bhi(g2.z) + pb.z*blo(g2.w) + pb.w*bhi(g2.w);
            u3 += pa.x*blo(g3.x) + pa.y*bhi(g3.x) + pa.z*blo(g3.y) + pa.w*bhi(g3.y)
                + pb.x*blo(g3.z) + pb.y*bhi(g3.z) + pb.z*blo(g3.w) + pb.w*bhi(g3.w);
        }
        float nsq = p0 * (u0 + diagF[lane] * p0)
                  + p1 * (u1 + diagF[lane + 64] * p1)
                  + p2 * (u2 + diagF[lane + 128] * p2);
        if (lane < 4) nsq += p3 * (u3 + diagF[lane + 192] * p3);
        #pragma unroll
        for (int off = 32; off; off >>= 1) nsq += __shfl_xor(nsq, off, 64);
        float inv = 1.f / fmaxf(sqrtf(fmaxf(nsq, 0.f)), 1e-12f);
        if (mk) inv = 0.f;
        wacc[wave][lane]       += p0 * inv;
        wacc[wave][lane + 64]  += p1 * inv;
        wacc[wave][lane + 128] += p2 * inv;
        if (lane < 4) wacc[wave][lane + 192] += p3 * inv;
    }
    __syncthreads();
    if (tid < 196) {
        float ws = 0.f;
        #pragma unroll
        for (int w = 0; w < 8; ++w) ws += wacc[w][tid];
        wacc[0][tid] = ws;
    }
    __syncthreads();

    float acc0 = 0.f, acc1 = 0.f;
    const float* vb = VE + (size_t)v * 196 * DD + tid;
    for (int j = 0; j < 196; j += 2) {
        acc0 = fmaf(wacc[0][j],     vb[(size_t)j * DD],       acc0);
        acc1 = fmaf(wacc[0][j + 1], vb[(size_t)(j + 1) * DD], acc1);
    }
    bacc[((size_t)v * 32 + t) * DD + tid] = acc0 + acc1;
}

// ---------- final: out[t,v] = dot(a[t,v,:], b[v,t,:]) / 12544 ----------
__global__ __launch_bounds__(64)
void final_dot(const float* __restrict__ aacc, const float* __restrict__ bacc,
               float* __restrict__ out)
{
    const int t = blockIdx.x, v = blockIdx.y;
    const int lane = threadIdx.x;
    const float* ap = aacc + ((size_t)t * 32 + v) * DD + lane * 8;
    const float* bp = bacc + ((size_t)v * 32 + t) * DD + lane * 8;
    float4 a0 = *(const float4*)ap,       a1 = *(const float4*)(ap + 4);
    float4 b0 = *(const float4*)bp,       b1 = *(const float4*)(bp + 4);
    float acc = a0.x*b0.x + a0.y*b0.y + a0.z*b0.z + a0.w*b0.w
              + a1.x*b1.x + a1.y*b1.y + a1.z*b1.z + a1.w*b1.w;
    #pragma unroll
    for (int off = 32; off; off >>= 1) acc += __shfl_xor(acc, off, 64);
    if (lane == 0) out[(size_t)t * 32 + v] = acc * (1.f / 12544.f);
}

// ---------- launcher ----------
extern "C" void kernel_launch(void* const* d_in, const int* in_sizes, int n_in,
                              void* d_out, int out_size, void* d_ws, size_t ws_size,
                              hipStream_t stream)
{
    const float* VF   = (const float*)d_in[0];
    const float* TF   = (const float*)d_in[1];
    const int*   mask = (const int*)  d_in[2];
    const float* Wv   = (const float*)d_in[3];
    const float* bv   = (const float*)d_in[4];
    const float* Wt   = (const float*)d_in[5];
    const float* bt   = (const float*)d_in[6];
    const float* Wq   = (const float*)d_in[7];
    const float* Wk   = (const float*)d_in[8];
    float* out = (float*)d_out;

    float* ws = (float*)d_ws;
    size_t off = 0;
    // R1: VF2 (4.82M fl) -> {Qv 3.21M, Qt 1.05M} -> S (12.85M). size = S
    float* R1 = ws + off; off += (size_t)MV * MT;
    // R2: TF2 (1.57M) -> {Kv 3.21M, Kt 1.05M}. size = 4.26M
    float* R2 = ws + off; off += (size_t)MV * DD + (size_t)MT * DD;
    // R3: VN2 / Qv2 (both 6272x1024 bf16 = 3.21M fl)
    float* R3 = ws + off; off += (size_t)MV * DD;
    // R4: TN2 / Qt2 (1.05M fl)
    float* R4 = ws + off; off += (size_t)MT * DD;
    // R5: {Wv2,Wt2,Wq2,Wk2 = 1.31M} -> Kv2 (3.21M fl)
    float* R5 = ws + off; off += (size_t)MV * DD;
    // R6: Kt2 (1.05M fl)
    float* R6 = ws + off; off += (size_t)MT * DD;
    float* VE  = ws + off; off += (size_t)MV * DD;
    float* TE  = ws + off; off += (size_t)MT * DD;
    float* Gt  = ws + off; off += (size_t)32 * 64 * 64;
    float* Gv  = ws + off; off += (size_t)32 * 196 * 196;
    float* Aac = ws + off; off += (size_t)32 * 32 * DD;
    float* Bac = ws + off; off += (size_t)32 * 32 * DD;

    u16* VF2 = (u16*)R1;
    u16* TF2 = (u16*)R2;
    u16* VN2 = (u16*)R3;  u16* Qv2 = (u16*)R3;
    u16* TN2 = (u16*)R4;  u16* Qt2 = (u16*)R4;
    u16* Wv2 = (u16*)R5;
    u16* Wt2 = Wv2 + (size_t)512 * 1536;
    u16* Wq2 = Wt2 + (size_t)512 * 1536;
    u16* Wk2 = Wq2 + (size_t)512 * 1024;
    u16* Kv2 = (u16*)R5;           // after W2 dead
    u16* Kt2 = (u16*)R6;
    float* Qv = R1;
    float* Qt = R1 + (size_t)MV * DD;
    float* Kv = R2;
    float* Kt = R2 + (size_t)MV * DD;
    float* S  = R1;

    // phase 1: conversions to split-bf16 tiled form
    conv_split<<<(MV * 96 + 255) / 256, 256, 0, stream>>>(VF, VF2, MV, 768);
    conv_split<<<(MT * 96 + 255) / 256, 256, 0, stream>>>(TF, TF2, MT, 768);
    conv_split<<<(512 * 96 + 255) / 256, 256, 0, stream>>>(Wv, Wv2, 512, 768);
    conv_split<<<(512 * 96 + 255) / 256, 256, 0, stream>>>(Wt, Wt2, 512, 768);
    conv_split<<<(512 * 64 + 255) / 256, 256, 0, stream>>>(Wq, Wq2, 512, 512);
    conv_split<<<(512 * 64 + 255) / 256, 256, 0, stream>>>(Wk, Wk2, 512, 512);

    // phase 2: embeds (+bias)
    gemm_split_nt<<<dim3(4, 49), 256, 0, stream>>>(VF2, Wv2, bv, VE, MV, 512, 768, 1);
    gemm_split_nt<<<dim3(4, 16), 256, 0, stream>>>(TF2, Wt2, bt, TE, MT, 512, 768, 1);

    // phase 3: rownorm->split + grams
    rownorm_conv<<<MV / 4, 256, 0, stream>>>(VE, VN2, MV);
    rownorm_conv<<<MT / 4, 256, 0, stream>>>(TE, TN2, MT);
    gram_batched<<<dim3(1, 1, 32), 256, 0, stream>>>(TE, Gt, 64);
    gram_batched<<<dim3(4, 4, 32), 256, 0, stream>>>(VE, Gv, 196);

    // phase 4: projections
    gemm_split_nt<<<dim3(4, 49), 256, 0, stream>>>(VN2, Wq2, nullptr, Qv, MV, 512, 512, 0);
    gemm_split_nt<<<dim3(4, 49), 256, 0, stream>>>(VN2, Wk2, nullptr, Kv, MV, 512, 512, 0);
    gemm_split_nt<<<dim3(4, 16), 256, 0, stream>>>(TN2, Wq2, nullptr, Qt, MT, 512, 512, 0);
    gemm_split_nt<<<dim3(4, 16), 256, 0, stream>>>(TN2, Wk2, nullptr, Kt, MT, 512, 512, 0);

    // phase 5: normalize + split-convert projections
    rownorm_conv<<<MV / 4, 256, 0, stream>>>(Qv, Qv2, MV);
    rownorm_conv<<<MV / 4, 256, 0, stream>>>(Kv, Kv2, MV);
    rownorm_conv<<<MT / 4, 256, 0, stream>>>(Qt, Qt2, MT);
    rownorm_conv<<<MT / 4, 256, 0, stream>>>(Kt, Kt2, MT);

    // phase 6: S1 = Qv*Kt^T -> att_text
    gemm_split_nt<<<dim3(16, 49), 256, 0, stream>>>(Qv2, Kt2, nullptr, S, MV, MT, 512, 0);
    att_text_stage<<<dim3(32, 32), 256, 0, stream>>>(S, Gt, TE, mask, Aac);

    // phase 7: S2 = Qt*Kv^T (reuses S) -> att_vis
    gemm_split_nt<<<dim3(49, 16), 256, 0, stream>>>(Qt2, Kv2, nullptr, S, MT, MV, 512, 0);
    att_vis_stage<<<dim3(32, 32), 512, 0, stream>>>(S, Gv, VE, mask, Bac);

    final_dot<<<dim3(32, 32), 64, 0, stream>>>(Aac, Bac, out);
}

// Round 6
// 673.458 us; speedup vs baseline: 2.3125x; 1.2668x over previous
//
#include <hip/hip_runtime.h>
#include <math.h>

#define BV 32
#define LV 196
#define DV 768
#define BT 32
#define LT 64
#define DD 512
#define MV (BV*LV)   /* 6272 */
#define MT (BT*LT)   /* 2048 */
#define TEMPF 20.0f
#define NEGF  -1.0e9f

typedef unsigned short u16;
typedef unsigned int   u32;
typedef short bf16x8 __attribute__((ext_vector_type(8)));
typedef float f32x4  __attribute__((ext_vector_type(4)));

// ---------- helpers ----------
__device__ __forceinline__ u16 f2bf(float f) {
    u32 u = __float_as_uint(f);
    u32 r = u + 0x7fffu + ((u >> 16) & 1u);
    return (u16)(r >> 16);
}
__device__ __forceinline__ float bf2f(u16 h) { return __uint_as_float(((u32)h) << 16); }

// Tiled-swizzled bf16 layout: matrix stored as 128x64 tiles (8192 ushorts).
// Element (row, ke): byte row*128 + (((ke>>3)^(row&7))<<4) + (ke&7)*2
// = the LDS image gemm wants (linear global_load_lds dest + swizzled ds_read).
__device__ __forceinline__ size_t tiled_chunk_off(int m, int kk, int KB2) {
    int rowBlk = m >> 7, row = m & 127;
    int kBlk = kk >> 6, ke = kk & 63;
    return ((size_t)(rowBlk * KB2 + kBlk) << 13) + row * 64 + ((((ke >> 3) ^ (row & 7)) << 4) >> 1);
}

// ---------- conv: X fp32 [M][K] -> X2 bf16 tiled [hi | lo] (K2 = 2K) ----------
__global__ __launch_bounds__(256)
void conv_split(const float* __restrict__ X, u16* __restrict__ X2, int M, int K)
{
    int gid = blockIdx.x * 256 + threadIdx.x;
    int perRow = K >> 3;
    if (gid >= M * perRow) return;
    int m = gid / perRow, k8 = (gid - m * perRow) << 3;
    const float* xp = X + (size_t)m * K + k8;
    float x[8];
    *(float4*)&x[0] = *(const float4*)xp;
    *(float4*)&x[4] = *(const float4*)(xp + 4);
    union { u16 h[8]; uint4 v; } hi, lo;
    #pragma unroll
    for (int e = 0; e < 8; ++e) {
        hi.h[e] = f2bf(x[e]);
        lo.h[e] = f2bf(x[e] - bf2f(hi.h[e]));
    }
    int KB2 = K >> 5;
    *(uint4*)&X2[tiled_chunk_off(m, k8, KB2)]     = hi.v;
    *(uint4*)&X2[tiled_chunk_off(m, K + k8, KB2)] = lo.v;
}

// ---------- fused rownorm + split conv (rows of 512) ----------
__global__ __launch_bounds__(256)
void rownorm_conv(const float* __restrict__ X, u16* __restrict__ X2, int M)
{
    const int row  = blockIdx.x * 4 + (threadIdx.x >> 6);
    const int lane = threadIdx.x & 63;
    const float* ip = X + (size_t)row * DD + lane * 8;
    float x[8];
    *(float4*)&x[0] = *(const float4*)ip;
    *(float4*)&x[4] = *(const float4*)(ip + 4);
    float ss = 0.f;
    #pragma unroll
    for (int e = 0; e < 8; ++e) ss += x[e] * x[e];
    #pragma unroll
    for (int off = 32; off; off >>= 1) ss += __shfl_xor(ss, off, 64);
    const float inv = 1.f / fmaxf(sqrtf(ss), 1e-12f);
    union { u16 h[8]; uint4 v; } hi, lo;
    #pragma unroll
    for (int e = 0; e < 8; ++e) {
        float xv = x[e] * inv;
        hi.h[e] = f2bf(xv);
        lo.h[e] = f2bf(xv - bf2f(hi.h[e]));
    }
    const int k8 = lane * 8, KB2 = 16;  // K=512
    *(uint4*)&X2[tiled_chunk_off(row, k8, KB2)]       = hi.v;
    *(uint4*)&X2[tiled_chunk_off(row, DD + k8, KB2)]  = lo.v;
}

// ---------- split-bf16 MFMA GEMM NT: C[M,N] = A*B^T (+bias) ----------
__device__ __forceinline__ void gload16(const u16* g, u16* l) {
    __builtin_amdgcn_global_load_lds((const __attribute__((address_space(1))) u32*)g,
                                     (__attribute__((address_space(3))) u32*)l, 16, 0, 0);
}

__global__ __launch_bounds__(256, 2)
void gemm_split_nt(const u16* __restrict__ A2, const u16* __restrict__ B2,
                   const float* __restrict__ bias, float* __restrict__ C,
                   int M, int N, int K, int hasBias)
{
    const int KB  = K >> 6;
    const int KB2 = KB * 2;
    const int bm = blockIdx.y, bn = blockIdx.x;
    const int tid = threadIdx.x;
    const int w = tid >> 6, lane = tid & 63;
    const int wr = (w >> 1) << 6, wc = (w & 1) << 6;
    const int fr = lane & 15, fq = lane >> 4;

    __shared__ u16 As[2][8192];
    __shared__ u16 Bs[2][8192];

    f32x4 acc[4][4];
    #pragma unroll
    for (int i = 0; i < 4; ++i)
        #pragma unroll
        for (int j = 0; j < 4; ++j) acc[i][j] = (f32x4){0.f, 0.f, 0.f, 0.f};

    const int swz = (fr & 7) << 4;
    const int aoff0 = ((wr + fr) << 7) >> 1;
    const int boff0 = ((wc + fr) << 7) >> 1;
    const int k0 = ((fq << 4) ^ swz) >> 1;
    const int k1 = ((64 + (fq << 4)) ^ swz) >> 1;

    const int c4 = w * 4;
    const int laneOff = c4 * 512 + lane * 8;

    const int T = 3 * KB;
    int cur = 0;

    {
        const u16* ag = A2 + (((size_t)(bm * KB2)) << 13) + laneOff;
        const u16* bg = B2 + (((size_t)(bn * KB2)) << 13) + laneOff;
        #pragma unroll
        for (int i = 0; i < 4; ++i) {
            gload16(ag + i * 512, &As[0][(c4 + i) * 512]);
            gload16(bg + i * 512, &Bs[0][(c4 + i) * 512]);
        }
    }
    __syncthreads();

    for (int t = 0; t < T; ++t) {
        if (t + 1 < T) {
            int tn = t + 1, ab, bb;
            if (tn < KB)           { ab = tn;          bb = tn; }
            else if (tn < 2 * KB)  { ab = tn - KB;     bb = tn; }
            else                   { ab = tn - KB;     bb = tn - 2 * KB; }
            const u16* ag = A2 + (((size_t)(bm * KB2 + ab)) << 13) + laneOff;
            const u16* bg = B2 + (((size_t)(bn * KB2 + bb)) << 13) + laneOff;
            int nb = cur ^ 1;
            #pragma unroll
            for (int i = 0; i < 4; ++i) {
                gload16(ag + i * 512, &As[nb][(c4 + i) * 512]);
                gload16(bg + i * 512, &Bs[nb][(c4 + i) * 512]);
            }
        }
        #pragma unroll
        for (int ks = 0; ks < 2; ++ks) {
            const int kk = ks ? k1 : k0;
            bf16x8 af[4], bfv[4];
            #pragma unroll
            for (int mi = 0; mi < 4; ++mi)
                af[mi] = *(const bf16x8*)&As[cur][aoff0 + mi * 1024 + kk];
            #pragma unroll
            for (int ni = 0; ni < 4; ++ni)
                bfv[ni] = *(const bf16x8*)&Bs[cur][boff0 + ni * 1024 + kk];
            #pragma unroll
            for (int mi = 0; mi < 4; ++mi)
                #pragma unroll
                for (int ni = 0; ni < 4; ++ni)
                    acc[mi][ni] = __builtin_amdgcn_mfma_f32_16x16x32_bf16(
                        af[mi], bfv[ni], acc[mi][ni], 0, 0, 0);
        }
        __syncthreads();
        cur ^= 1;
    }

    #pragma unroll
    for (int ni = 0; ni < 4; ++ni) {
        const int col = (bn << 7) + wc + ni * 16 + fr;
        const float badd = hasBias ? bias[col] : 0.f;
        #pragma unroll
        for (int mi = 0; mi < 4; ++mi) {
            #pragma unroll
            for (int j = 0; j < 4; ++j) {
                const int row = (bm << 7) + wr + mi * 16 + fq * 4 + j;
                C[(size_t)row * N + col] = acc[mi][ni][j] + badd;
            }
        }
    }
}

// ---------- batched U = P * G^T (single-pass bf16, K=N=256 padded) ----------
// A2: P tiled per v (16 rowBlk x 4 kBlk). B2: Gpad tiled per v (2 rowBlk x 4 kBlk).
// U fp32 [v][2048][196] (cols >=196 dropped).
__global__ __launch_bounds__(256, 2)
void gemm_pg(const u16* __restrict__ P, const u16* __restrict__ G,
             float* __restrict__ U)
{
    const int v = blockIdx.z;
    const int bm = blockIdx.y, bn = blockIdx.x;
    const int tid = threadIdx.x;
    const int w = tid >> 6, lane = tid & 63;
    const int wr = (w >> 1) << 6, wc = (w & 1) << 6;
    const int fr = lane & 15, fq = lane >> 4;

    const u16* A2 = P + ((size_t)v << 19);   // 2048*256
    const u16* B2 = G + ((size_t)v << 16);   // 256*256

    __shared__ u16 As[2][8192];
    __shared__ u16 Bs[2][8192];

    f32x4 acc[4][4];
    #pragma unroll
    for (int i = 0; i < 4; ++i)
        #pragma unroll
        for (int j = 0; j < 4; ++j) acc[i][j] = (f32x4){0.f, 0.f, 0.f, 0.f};

    const int swz = (fr & 7) << 4;
    const int aoff0 = ((wr + fr) << 7) >> 1;
    const int boff0 = ((wc + fr) << 7) >> 1;
    const int k0 = ((fq << 4) ^ swz) >> 1;
    const int k1 = ((64 + (fq << 4)) ^ swz) >> 1;
    const int c4 = w * 4;
    const int laneOff = c4 * 512 + lane * 8;

    int cur = 0;
    {
        const u16* ag = A2 + (((size_t)(bm * 4)) << 13) + laneOff;
        const u16* bg = B2 + (((size_t)(bn * 4)) << 13) + laneOff;
        #pragma unroll
        for (int i = 0; i < 4; ++i) {
            gload16(ag + i * 512, &As[0][(c4 + i) * 512]);
            gload16(bg + i * 512, &Bs[0][(c4 + i) * 512]);
        }
    }
    __syncthreads();

    for (int t = 0; t < 4; ++t) {
        if (t + 1 < 4) {
            const u16* ag = A2 + (((size_t)(bm * 4 + t + 1)) << 13) + laneOff;
            const u16* bg = B2 + (((size_t)(bn * 4 + t + 1)) << 13) + laneOff;
            int nb = cur ^ 1;
            #pragma unroll
            for (int i = 0; i < 4; ++i) {
                gload16(ag + i * 512, &As[nb][(c4 + i) * 512]);
                gload16(bg + i * 512, &Bs[nb][(c4 + i) * 512]);
            }
        }
        #pragma unroll
        for (int ks = 0; ks < 2; ++ks) {
            const int kk = ks ? k1 : k0;
            bf16x8 af[4], bfv[4];
            #pragma unroll
            for (int mi = 0; mi < 4; ++mi)
                af[mi] = *(const bf16x8*)&As[cur][aoff0 + mi * 1024 + kk];
            #pragma unroll
            for (int ni = 0; ni < 4; ++ni)
                bfv[ni] = *(const bf16x8*)&Bs[cur][boff0 + ni * 1024 + kk];
            #pragma unroll
            for (int mi = 0; mi < 4; ++mi)
                #pragma unroll
                for (int ni = 0; ni < 4; ++ni)
                    acc[mi][ni] = __builtin_amdgcn_mfma_f32_16x16x32_bf16(
                        af[mi], bfv[ni], acc[mi][ni], 0, 0, 0);
        }
        __syncthreads();
        cur ^= 1;
    }

    float* Uv = U + (size_t)v * MT * 196;
    #pragma unroll
    for (int ni = 0; ni < 4; ++ni) {
        const int col = (bn << 7) + wc + ni * 16 + fr;
        if (col < 196) {
            #pragma unroll
            for (int mi = 0; mi < 4; ++mi) {
                #pragma unroll
                for (int j = 0; j < 4; ++j) {
                    const int row = (bm << 7) + wr + mi * 16 + fq * 4 + j;
                    Uv[(size_t)row * 196 + col] = acc[mi][ni][j];
                }
            }
        }
    }
}

// ---------- batched Gram (fp32 out) for Gt (Mg=64) ----------
__global__ __launch_bounds__(256)
void gram_batched(const float* __restrict__ X, float* __restrict__ G, int Mg)
{
    const int bat = blockIdx.z;
    const int it = blockIdx.y, jt = blockIdx.x;
    const int tid = threadIdx.x;
    const int tx = tid & 15, ty = tid >> 4;
    __shared__ float Xa[32][68];
    __shared__ float Xb[32][68];
    const float* Xbase = X + (size_t)bat * Mg * DD;

    float acc[4][4];
    #pragma unroll
    for (int i = 0; i < 4; ++i)
        #pragma unroll
        for (int j = 0; j < 4; ++j) acc[i][j] = 0.f;

    for (int k0 = 0; k0 < DD; k0 += 32) {
        #pragma unroll
        for (int i = 0; i < 2; ++i) {
            int idx = tid + 256 * i;
            int row = idx >> 3;
            int kc  = (idx & 7) << 2;
            int ra = it * 64 + row; ra = (ra < Mg) ? ra : (Mg - 1);
            int rb = jt * 64 + row; rb = (rb < Mg) ? rb : (Mg - 1);
            float4 av = *(const float4*)(Xbase + (size_t)ra * DD + k0 + kc);
            Xa[kc + 0][row] = av.x; Xa[kc + 1][row] = av.y;
            Xa[kc + 2][row] = av.z; Xa[kc + 3][row] = av.w;
            float4 bv = *(const float4*)(Xbase + (size_t)rb * DD + k0 + kc);
            Xb[kc + 0][row] = bv.x; Xb[kc + 1][row] = bv.y;
            Xb[kc + 2][row] = bv.z; Xb[kc + 3][row] = bv.w;
        }
        __syncthreads();
        #pragma unroll 8
        for (int kk = 0; kk < 32; ++kk) {
            float a[4], b[4];
            *(float4*)a = *(const float4*)&Xa[kk][ty * 4];
            *(float4*)b = *(const float4*)&Xb[kk][tx * 4];
            #pragma unroll
            for (int i = 0; i < 4; ++i)
                #pragma unroll
                for (int j = 0; j < 4; ++j)
                    acc[i][j] = fmaf(a[i], b[j], acc[i][j]);
        }
        __syncthreads();
    }

    #pragma unroll
    for (int i = 0; i < 4; ++i) {
        int row = it * 64 + ty * 4 + i;
        int col = jt * 64 + tx * 4;
        if (row < Mg && col < Mg) {
            float* gp = G + ((size_t)bat * Mg + row) * Mg + col;
            *(float4*)gp = make_float4(acc[i][0], acc[i][1], acc[i][2], acc[i][3]);
        }
    }
}

// ---------- Gram for VE (196x196) -> bf16 tiled 256x256, zero diag + fp32 diag ----------
__global__ __launch_bounds__(256)
void gram_vis(const float* __restrict__ X, u16* __restrict__ Gp,
              float* __restrict__ diagF)
{
    const int bat = blockIdx.z;
    const int it = blockIdx.y, jt = blockIdx.x;
    const int tid = threadIdx.x;
    const int tx = tid & 15, ty = tid >> 4;
    __shared__ float Xa[32][68];
    __shared__ float Xb[32][68];
    const float* Xbase = X + (size_t)bat * 196 * DD;

    float acc[4][4];
    #pragma unroll
    for (int i = 0; i < 4; ++i)
        #pragma unroll
        for (int j = 0; j < 4; ++j) acc[i][j] = 0.f;

    for (int k0 = 0; k0 < DD; k0 += 32) {
        #pragma unroll
        for (int i = 0; i < 2; ++i) {
            int idx = tid + 256 * i;
            int row = idx >> 3;
            int kc  = (idx & 7) << 2;
            int ra = it * 64 + row; ra = (ra < 196) ? ra : 195;
            int rb = jt * 64 + row; rb = (rb < 196) ? rb : 195;
            float4 av = *(const float4*)(Xbase + (size_t)ra * DD + k0 + kc);
            Xa[kc + 0][row] = av.x; Xa[kc + 1][row] = av.y;
            Xa[kc + 2][row] = av.z; Xa[kc + 3][row] = av.w;
            float4 bv = *(const float4*)(Xbase + (size_t)rb * DD + k0 + kc);
            Xb[kc + 0][row] = bv.x; Xb[kc + 1][row] = bv.y;
            Xb[kc + 2][row] = bv.z; Xb[kc + 3][row] = bv.w;
        }
        __syncthreads();
        #pragma unroll 8
        for (int kk = 0; kk < 32; ++kk) {
            float a[4], b[4];
            *(float4*)a = *(const float4*)&Xa[kk][ty * 4];
            *(float4*)b = *(const float4*)&Xb[kk][tx * 4];
            #pragma unroll
            for (int i = 0; i < 4; ++i)
                #pragma unroll
                for (int j = 0; j < 4; ++j)
                    acc[i][j] = fmaf(a[i], b[j], acc[i][j]);
        }
        __syncthreads();
    }

    // write bf16 tiled (B-operand layout: rows=j, cols=l), zero diag & pad
    u16* Gv = Gp + ((size_t)bat << 16);
    #pragma unroll
    for (int i = 0; i < 4; ++i) {
        const int row = it * 64 + ty * 4 + i;     // j
        #pragma unroll
        for (int jj = 0; jj < 4; ++jj) {
            const int col = jt * 64 + tx * 4 + jj; // l
            float val = acc[i][jj];
            u16 o = (row < 196 && col < 196 && row != col) ? f2bf(val) : (u16)0;
            Gv[tiled_chunk_off(row, col & ~7, 4) + (col & 7)] = o;
            if (row == col && row < 196) diagF[bat * 196 + row] = val;
        }
    }
}

// ---------- row-softmax of S2 per (row, v) -> P bf16 tiled, K-padded to 256 ----------
__global__ __launch_bounds__(256)
void softmax_vis(const float* __restrict__ S2, u16* __restrict__ P)
{
    const int row  = blockIdx.x;
    const int wave = threadIdx.x >> 6, lane = threadIdx.x & 63;
    const int v = blockIdx.y * 4 + wave;
    __shared__ float pl[4][256];

    const float* srow = S2 + (size_t)row * MV + v * 196;
    float l0 = fmaxf(srow[lane], 0.f) * TEMPF;
    float l1 = fmaxf(srow[lane + 64], 0.f) * TEMPF;
    float l2 = fmaxf(srow[lane + 128], 0.f) * TEMPF;
    float l3 = -3.0e38f;
    if (lane < 4) l3 = fmaxf(srow[lane + 192], 0.f) * TEMPF;
    float mx = fmaxf(fmaxf(l0, l1), fmaxf(l2, l3));
    #pragma unroll
    for (int off = 32; off; off >>= 1) mx = fmaxf(mx, __shfl_xor(mx, off, 64));
    float p0 = __expf(l0 - mx), p1 = __expf(l1 - mx), p2 = __expf(l2 - mx);
    float p3 = (lane < 4) ? __expf(l3 - mx) : 0.f;
    float sum = p0 + p1 + p2 + p3;
    #pragma unroll
    for (int off = 32; off; off >>= 1) sum += __shfl_xor(sum, off, 64);
    float rs = 1.f / sum;
    pl[wave][lane]       = p0 * rs;
    pl[wave][lane + 64]  = p1 * rs;
    pl[wave][lane + 128] = p2 * rs;
    if (lane < 4) pl[wave][lane + 192] = p3 * rs;
    else          pl[wave][lane + 192] = 0.f;   // zeros cols 196..255
    __syncthreads();

    if (lane < 32) {
        union { u16 h[8]; uint4 u; } c;
        #pragma unroll
        for (int e = 0; e < 8; ++e) c.h[e] = f2bf(pl[wave][lane * 8 + e]);
        u16* Pv = P + ((size_t)v << 19);
        *(uint4*)&Pv[tiled_chunk_off(row, lane * 8, 4)] = c.u;
    }
}

// ---------- per-row: nsq = p.U + p^2.diag -> inv; accumulate w ----------
__global__ __launch_bounds__(256)
void vis_norm_w(const float* __restrict__ U, const u16* __restrict__ P,
                const float* __restrict__ diagF, const int* __restrict__ mask,
                float* __restrict__ Wbuf)
{
    const int t = blockIdx.x, v = blockIdx.y;
    const int wave = threadIdx.x >> 6, lane = threadIdx.x & 63;
    __shared__ float wacc[4][200];

    for (int j = lane; j < 200; j += 64) wacc[wave][j] = 0.f;
    __syncthreads();

    const u16* Pv = P + ((size_t)v << 19);
    const float* dF = diagF + v * 196;
    const float d0 = dF[lane], d1 = dF[lane + 64], d2 = dF[lane + 128];
    const float d3 = (lane < 4) ? dF[lane + 192] : 0.f;

    for (int m = wave; m < 64; m += 4) {
        const int row = t * 64 + m;
        const float* urow = U + ((size_t)v * MT + row) * 196;
        const size_t base0 = tiled_chunk_off(row, lane & ~7, 4) + (lane & 7);
        float p0 = bf2f(Pv[base0]);
        float p1 = bf2f(Pv[tiled_chunk_off(row, (lane + 64) & ~7, 4) + (lane & 7)]);
        float p2 = bf2f(Pv[tiled_chunk_off(row, (lane + 128) & ~7, 4) + (lane & 7)]);
        float p3 = (lane < 4) ? bf2f(Pv[tiled_chunk_off(row, (lane + 192) & ~7, 4) + (lane & 7)]) : 0.f;
        float u0 = urow[lane], u1 = urow[lane + 64], u2 = urow[lane + 128];
        float u3 = (lane < 4) ? urow[lane + 192] : 0.f;
        float nsq = p0 * (u0 + d0 * p0) + p1 * (u1 + d1 * p1)
                  + p2 * (u2 + d2 * p2) + p3 * (u3 + d3 * p3);
        #pragma unroll
        for (int off = 32; off; off >>= 1) nsq += __shfl_xor(nsq, off, 64);
        float inv = 1.f / fmaxf(sqrtf(fmaxf(nsq, 0.f)), 1e-12f);
        if (mask[row]) inv = 0.f;
        wacc[wave][lane]       += p0 * inv;
        wacc[wave][lane + 64]  += p1 * inv;
        wacc[wave][lane + 128] += p2 * inv;
        if (lane < 4) wacc[wave][lane + 192] += p3 * inv;
    }
    __syncthreads();
    const int tid = threadIdx.x;
    if (tid < 196)
        Wbuf[((size_t)v * 32 + t) * 196 + tid] =
            wacc[0][tid] + wacc[1][tid] + wacc[2][tid] + wacc[3][tid];
}

// ---------- b[v][t][:] = w . VE_v ----------
__global__ __launch_bounds__(512)
void vis_b(const float* __restrict__ Wbuf, const float* __restrict__ VE,
           float* __restrict__ bacc)
{
    const int t = blockIdx.x, v = blockIdx.y;
    const int tid = threadIdx.x;
    __shared__ float wl[196];
    if (tid < 196) wl[tid] = Wbuf[((size_t)v * 32 + t) * 196 + tid];
    __syncthreads();
    float a0 = 0.f, a1 = 0.f;
    const float* vb = VE + (size_t)v * 196 * DD + tid;
    for (int j = 0; j < 196; j += 2) {
        a0 = fmaf(wl[j],     vb[(size_t)j * DD],       a0);
        a1 = fmaf(wl[j + 1], vb[(size_t)(j + 1) * DD], a1);
    }
    bacc[((size_t)v * 32 + t) * DD + tid] = a0 + a1;
}

// ---------- att_text: softmax(64) + Gram-norm + weight-reduce -> a[t][v][512] ----------
__global__ __launch_bounds__(256)
void att_text_stage(const float* __restrict__ S, const float* __restrict__ Gt,
                    const float* __restrict__ TE, const int* __restrict__ mask,
                    float* __restrict__ aacc)
{
    const int t = blockIdx.x, v = blockIdx.y;
    const int tid = threadIdx.x, wave = tid >> 6, lane = tid & 63;
    __shared__ float Gs[64][68];
    __shared__ float pbuf[4][64];
    __shared__ float wacc[4][64];

    {
        const float* gp = Gt + (size_t)t * 64 * 64;
        #pragma unroll
        for (int i = 0; i < 4; ++i) {
            int idx = tid + 256 * i;
            int row = idx >> 4;
            int c4  = (idx & 15) << 2;
            float4 g4 = *(const float4*)(gp + (size_t)idx * 4);
            *(float4*)&Gs[row][c4] = g4;
        }
    }
    wacc[wave][lane] = 0.f;
    const int mk = mask[t * 64 + lane];
    __syncthreads();

    for (int l = wave; l < LV; l += 4) {
        const int r = v * LV + l;
        float s = S[(size_t)r * MT + t * 64 + lane];
        float logit = mk ? NEGF : fmaxf(s, 0.f) * TEMPF;
        float mx = logit;
        #pragma unroll
        for (int off = 32; off; off >>= 1) mx = fmaxf(mx, __shfl_xor(mx, off, 64));
        float p = __expf(logit - mx);
        float sum = p;
        #pragma unroll
        for (int off = 32; off; off >>= 1) sum += __shfl_xor(sum, off, 64);
        p /= sum;
        pbuf[wave][lane] = p;
        float u = 0.f;
        #pragma unroll
        for (int mb = 0; mb < 64; mb += 4) {
            float4 p4 = *(const float4*)&pbuf[wave][mb];
            float4 g4 = *(const float4*)&Gs[lane][mb];
            u = fmaf(p4.x, g4.x, u); u = fmaf(p4.y, g4.y, u);
            u = fmaf(p4.z, g4.z, u); u = fmaf(p4.w, g4.w, u);
        }
        float nsq = p * u;
        #pragma unroll
        for (int off = 32; off; off >>= 1) nsq += __shfl_xor(nsq, off, 64);
        float inv = 1.f / fmaxf(sqrtf(fmaxf(nsq, 0.f)), 1e-12f);
        wacc[wave][lane] += p * inv;
    }
    __syncthreads();
    if (tid < 64)
        wacc[0][tid] = wacc[0][tid] + wacc[1][tid] + wacc[2][tid] + wacc[3][tid];
    __syncthreads();

    const int d = tid * 2;
    float a0 = 0.f, a1 = 0.f;
    const float* tb = TE + (size_t)(t * 64) * DD + d;
    for (int m = 0; m < 64; ++m) {
        float wm = wacc[0][m];
        float2 te = *(const float2*)(tb + (size_t)m * DD);
        a0 = fmaf(wm, te.x, a0);
        a1 = fmaf(wm, te.y, a1);
    }
    *(float2*)(aacc + ((size_t)t * 32 + v) * DD + d) = make_float2(a0, a1);
}

// ---------- final: out[t,v] = dot(a[t,v,:], b[v,t,:]) / 12544 ----------
__global__ __launch_bounds__(64)
void final_dot(const float* __restrict__ aacc, const float* __restrict__ bacc,
               float* __restrict__ out)
{
    const int t = blockIdx.x, v = blockIdx.y;
    const int lane = threadIdx.x;
    const float* ap = aacc + ((size_t)t * 32 + v) * DD + lane * 8;
    const float* bp = bacc + ((size_t)v * 32 + t) * DD + lane * 8;
    float4 a0 = *(const float4*)ap,       a1 = *(const float4*)(ap + 4);
    float4 b0 = *(const float4*)bp,       b1 = *(const float4*)(bp + 4);
    float acc = a0.x*b0.x + a0.y*b0.y + a0.z*b0.z + a0.w*b0.w
              + a1.x*b1.x + a1.y*b1.y + a1.z*b1.z + a1.w*b1.w;
    #pragma unroll
    for (int off = 32; off; off >>= 1) acc += __shfl_xor(acc, off, 64);
    if (lane == 0) out[(size_t)t * 32 + v] = acc * (1.f / 12544.f);
}

// ---------- launcher ----------
extern "C" void kernel_launch(void* const* d_in, const int* in_sizes, int n_in,
                              void* d_out, int out_size, void* d_ws, size_t ws_size,
                              hipStream_t stream)
{
    const float* VF   = (const float*)d_in[0];
    const float* TF   = (const float*)d_in[1];
    const int*   mask = (const int*)  d_in[2];
    const float* Wv   = (const float*)d_in[3];
    const float* bv   = (const float*)d_in[4];
    const float* Wt   = (const float*)d_in[5];
    const float* bt   = (const float*)d_in[6];
    const float* Wq   = (const float*)d_in[7];
    const float* Wk   = (const float*)d_in[8];
    float* out = (float*)d_out;

    float* ws = (float*)d_ws;
    size_t off = 0;
    // R1 (12.85M fl): VF2 -> Qv,Qt fp32 -> S (S1,S2) -> U
    float* R1 = ws + off; off += (size_t)MV * MT;
    // R2 (4.26M fl): TF2 -> Kv,Kt fp32 -> Wbuf
    float* R2 = ws + off; off += (size_t)MV * DD + (size_t)MT * DD;
    // R3..R6 (8.52M fl contiguous): VN2/Qv2, TN2/Qt2, W2s->Kv2, Kt2 -> P (8.39M)
    float* R3 = ws + off; off += (size_t)MV * DD;
    float* R4 = ws + off; off += (size_t)MT * DD;
    float* R5 = ws + off; off += (size_t)MV * DD;
    float* R6 = ws + off; off += (size_t)MT * DD;
    float* VE  = ws + off; off += (size_t)MV * DD;
    float* TE  = ws + off; off += (size_t)MT * DD;
    float* Gt  = ws + off; off += (size_t)32 * 64 * 64;
    float* GvR = ws + off; off += (size_t)32 * 196 * 196;  // Gpad(1.049M)+diagF(6272)
    float* Aac = ws + off; off += (size_t)32 * 32 * DD;
    float* Bac = ws + off; off += (size_t)32 * 32 * DD;

    u16* VF2 = (u16*)R1;
    u16* TF2 = (u16*)R2;
    u16* VN2 = (u16*)R3;  u16* Qv2 = (u16*)R3;
    u16* TN2 = (u16*)R4;  u16* Qt2 = (u16*)R4;
    u16* Wv2 = (u16*)R5;
    u16* Wt2 = Wv2 + (size_t)512 * 1536;
    u16* Wq2 = Wt2 + (size_t)512 * 1536;
    u16* Wk2 = Wq2 + (size_t)512 * 1024;
    u16* Kv2 = (u16*)R5;
    u16* Kt2 = (u16*)R6;
    float* Qv = R1;
    float* Qt = R1 + (size_t)MV * DD;
    float* Kv = R2;
    float* Kt = R2 + (size_t)MV * DD;
    float* S  = R1;
    float* U  = R1;
    u16*   P  = (u16*)R3;                 // 32*2048*256 u16 = 8.39M fl over R3..R6
    u16*   Gp = (u16*)GvR;                // 32*256*256 u16
    float* diagF = GvR + (size_t)32 * 256 * 256 / 2;
    float* Wbuf = R2;                     // 32*32*196 fl (Kv/Kt dead by then)

    // phase 1: conversions to split-bf16 tiled form
    conv_split<<<(MV * 96 + 255) / 256, 256, 0, stream>>>(VF, VF2, MV, 768);
    conv_split<<<(MT * 96 + 255) / 256, 256, 0, stream>>>(TF, TF2, MT, 768);
    conv_split<<<(512 * 96 + 255) / 256, 256, 0, stream>>>(Wv, Wv2, 512, 768);
    conv_split<<<(512 * 96 + 255) / 256, 256, 0, stream>>>(Wt, Wt2, 512, 768);
    conv_split<<<(512 * 64 + 255) / 256, 256, 0, stream>>>(Wq, Wq2, 512, 512);
    conv_split<<<(512 * 64 + 255) / 256, 256, 0, stream>>>(Wk, Wk2, 512, 512);

    // phase 2: embeds (+bias)
    gemm_split_nt<<<dim3(4, 49), 256, 0, stream>>>(VF2, Wv2, bv, VE, MV, 512, 768, 1);
    gemm_split_nt<<<dim3(4, 16), 256, 0, stream>>>(TF2, Wt2, bt, TE, MT, 512, 768, 1);

    // phase 3: rownorm->split + grams
    rownorm_conv<<<MV / 4, 256, 0, stream>>>(VE, VN2, MV);
    rownorm_conv<<<MT / 4, 256, 0, stream>>>(TE, TN2, MT);
    gram_batched<<<dim3(1, 1, 32), 256, 0, stream>>>(TE, Gt, 64);
    gram_vis<<<dim3(4, 4, 32), 256, 0, stream>>>(VE, Gp, diagF);

    // phase 4: projections
    gemm_split_nt<<<dim3(4, 49), 256, 0, stream>>>(VN2, Wq2, nullptr, Qv, MV, 512, 512, 0);
    gemm_split_nt<<<dim3(4, 49), 256, 0, stream>>>(VN2, Wk2, nullptr, Kv, MV, 512, 512, 0);
    gemm_split_nt<<<dim3(4, 16), 256, 0, stream>>>(TN2, Wq2, nullptr, Qt, MT, 512, 512, 0);
    gemm_split_nt<<<dim3(4, 16), 256, 0, stream>>>(TN2, Wk2, nullptr, Kt, MT, 512, 512, 0);

    // phase 5: normalize + split-convert projections
    rownorm_conv<<<MV / 4, 256, 0, stream>>>(Qv, Qv2, MV);
    rownorm_conv<<<MV / 4, 256, 0, stream>>>(Kv, Kv2, MV);
    rownorm_conv<<<MT / 4, 256, 0, stream>>>(Qt, Qt2, MT);
    rownorm_conv<<<MT / 4, 256, 0, stream>>>(Kt, Kt2, MT);

    // phase 6: S1 = Qv2*Kt2^T -> att_text
    gemm_split_nt<<<dim3(16, 49), 256, 0, stream>>>(Qv2, Kt2, nullptr, S, MV, MT, 512, 0);
    att_text_stage<<<dim3(32, 32), 256, 0, stream>>>(S, Gt, TE, mask, Aac);

    // phase 7: S2 = Qt2*Kv2^T -> softmax -> U=P*G -> norms/w -> b
    gemm_split_nt<<<dim3(49, 16), 256, 0, stream>>>(Qt2, Kv2, nullptr, S, MT, MV, 512, 0);
    softmax_vis<<<dim3(MT, 8), 256, 0, stream>>>(S, P);
    gemm_pg<<<dim3(2, 16, 32), 256, 0, stream>>>(P, Gp, U);
    vis_norm_w<<<dim3(32, 32), 256, 0, stream>>>(U, P, diagF, mask, Wbuf);
    vis_b<<<dim3(32, 32), 512, 0, stream>>>(Wbuf, VE, Bac);

    final_dot<<<dim3(32, 32), 64, 0, stream>>>(Aac, Bac, out);
}

// Round 9
// 660.543 us; speedup vs baseline: 2.3578x; 1.0196x over previous
//
#include <hip/hip_runtime.h>
#include <math.h>

#define BV 32
#define LV 196
#define DV 768
#define BT 32
#define LT 64
#define DD 512
#define MV (BV*LV)   /* 6272 */
#define MT (BT*LT)   /* 2048 */
#define TEMPF 20.0f
#define NEGF  -1.0e9f

typedef unsigned short u16;
typedef unsigned int   u32;
typedef short bf16x8 __attribute__((ext_vector_type(8)));
typedef float f32x4  __attribute__((ext_vector_type(4)));

// ---------- helpers ----------
__device__ __forceinline__ u16 f2bf(float f) {
    u32 u = __float_as_uint(f);
    u32 r = u + 0x7fffu + ((u >> 16) & 1u);
    return (u16)(r >> 16);
}
__device__ __forceinline__ float bf2f(u16 h) { return __uint_as_float(((u32)h) << 16); }

// Tiled-swizzled bf16 layout: matrix stored as 128x64 tiles (8192 ushorts).
// Element (row, ke): byte row*128 + (((ke>>3)^(row&7))<<4) + (ke&7)*2
__device__ __forceinline__ size_t tiled_chunk_off(int m, int kk, int KB2) {
    int rowBlk = m >> 7, row = m & 127;
    int kBlk = kk >> 6, ke = kk & 63;
    return ((size_t)(rowBlk * KB2 + kBlk) << 13) + row * 64 + ((((ke >> 3) ^ (row & 7)) << 4) >> 1);
}

// ---------- conv: X fp32 [M][K] -> X2 bf16 tiled [hi | lo] (K2 = 2K) ----------
__global__ __launch_bounds__(256)
void conv_split(const float* __restrict__ X, u16* __restrict__ X2, int M, int K)
{
    int gid = blockIdx.x * 256 + threadIdx.x;
    int perRow = K >> 3;
    if (gid >= M * perRow) return;
    int m = gid / perRow, k8 = (gid - m * perRow) << 3;
    const float* xp = X + (size_t)m * K + k8;
    float x[8];
    *(float4*)&x[0] = *(const float4*)xp;
    *(float4*)&x[4] = *(const float4*)(xp + 4);
    union { u16 h[8]; uint4 v; } hi, lo;
    #pragma unroll
    for (int e = 0; e < 8; ++e) {
        hi.h[e] = f2bf(x[e]);
        lo.h[e] = f2bf(x[e] - bf2f(hi.h[e]));
    }
    int KB2 = K >> 5;
    *(uint4*)&X2[tiled_chunk_off(m, k8, KB2)]     = hi.v;
    *(uint4*)&X2[tiled_chunk_off(m, K + k8, KB2)] = lo.v;
}

// ---------- fused rownorm + split conv (rows of 512) ----------
__global__ __launch_bounds__(256)
void rownorm_conv(const float* __restrict__ X, u16* __restrict__ X2, int M)
{
    const int row  = blockIdx.x * 4 + (threadIdx.x >> 6);
    const int lane = threadIdx.x & 63;
    const float* ip = X + (size_t)row * DD + lane * 8;
    float x[8];
    *(float4*)&x[0] = *(const float4*)ip;
    *(float4*)&x[4] = *(const float4*)(ip + 4);
    float ss = 0.f;
    #pragma unroll
    for (int e = 0; e < 8; ++e) ss += x[e] * x[e];
    #pragma unroll
    for (int off = 32; off; off >>= 1) ss += __shfl_xor(ss, off, 64);
    const float inv = 1.f / fmaxf(sqrtf(ss), 1e-12f);
    union { u16 h[8]; uint4 v; } hi, lo;
    #pragma unroll
    for (int e = 0; e < 8; ++e) {
        float xv = x[e] * inv;
        hi.h[e] = f2bf(xv);
        lo.h[e] = f2bf(xv - bf2f(hi.h[e]));
    }
    const int k8 = lane * 8, KB2 = 16;  // K=512
    *(uint4*)&X2[tiled_chunk_off(row, k8, KB2)]       = hi.v;
    *(uint4*)&X2[tiled_chunk_off(row, DD + k8, KB2)]  = lo.v;
}

// ---------- bf16 MFMA GEMM NT: C[M,N] = A*B^T (+bias) ----------
// split=1: 3 passes (Ah*Bh + Ah*Bl + Al*Bh). split=0: single pass (hi only).
__device__ __forceinline__ void gload16(const u16* g, u16* l) {
    __builtin_amdgcn_global_load_lds((const __attribute__((address_space(1))) u32*)g,
                                     (__attribute__((address_space(3))) u32*)l, 16, 0, 0);
}

__global__ __launch_bounds__(256, 2)
void gemm_split_nt(const u16* __restrict__ A2, const u16* __restrict__ B2,
                   const float* __restrict__ bias, float* __restrict__ C,
                   int M, int N, int K, int hasBias, int split)
{
    const int KB  = K >> 6;
    const int KB2 = KB * 2;
    const int bm = blockIdx.y, bn = blockIdx.x;
    const int tid = threadIdx.x;
    const int w = tid >> 6, lane = tid & 63;
    const int wr = (w >> 1) << 6, wc = (w & 1) << 6;
    const int fr = lane & 15, fq = lane >> 4;

    __shared__ u16 As[2][8192];
    __shared__ u16 Bs[2][8192];

    f32x4 acc[4][4];
    #pragma unroll
    for (int i = 0; i < 4; ++i)
        #pragma unroll
        for (int j = 0; j < 4; ++j) acc[i][j] = (f32x4){0.f, 0.f, 0.f, 0.f};

    const int swz = (fr & 7) << 4;
    const int aoff0 = ((wr + fr) << 7) >> 1;
    const int boff0 = ((wc + fr) << 7) >> 1;
    const int k0 = ((fq << 4) ^ swz) >> 1;
    const int k1 = ((64 + (fq << 4)) ^ swz) >> 1;

    const int c4 = w * 4;
    const int laneOff = c4 * 512 + lane * 8;

    const int T = split ? 3 * KB : KB;
    int cur = 0;

    {
        const u16* ag = A2 + (((size_t)(bm * KB2)) << 13) + laneOff;
        const u16* bg = B2 + (((size_t)(bn * KB2)) << 13) + laneOff;
        #pragma unroll
        for (int i = 0; i < 4; ++i) {
            gload16(ag + i * 512, &As[0][(c4 + i) * 512]);
            gload16(bg + i * 512, &Bs[0][(c4 + i) * 512]);
        }
    }
    __syncthreads();

    for (int t = 0; t < T; ++t) {
        if (t + 1 < T) {
            int tn = t + 1, ab, bb;
            if (tn < KB)           { ab = tn;          bb = tn; }
            else if (tn < 2 * KB)  { ab = tn - KB;     bb = tn; }
            else                   { ab = tn - KB;     bb = tn - 2 * KB; }
            const u16* ag = A2 + (((size_t)(bm * KB2 + ab)) << 13) + laneOff;
            const u16* bg = B2 + (((size_t)(bn * KB2 + bb)) << 13) + laneOff;
            int nb = cur ^ 1;
            #pragma unroll
            for (int i = 0; i < 4; ++i) {
                gload16(ag + i * 512, &As[nb][(c4 + i) * 512]);
                gload16(bg + i * 512, &Bs[nb][(c4 + i) * 512]);
            }
        }
        #pragma unroll
        for (int ks = 0; ks < 2; ++ks) {
            const int kk = ks ? k1 : k0;
            bf16x8 af[4], bfv[4];
            #pragma unroll
            for (int mi = 0; mi < 4; ++mi)
                af[mi] = *(const bf16x8*)&As[cur][aoff0 + mi * 1024 + kk];
            #pragma unroll
            for (int ni = 0; ni < 4; ++ni)
                bfv[ni] = *(const bf16x8*)&Bs[cur][boff0 + ni * 1024 + kk];
            #pragma unroll
            for (int mi = 0; mi < 4; ++mi)
                #pragma unroll
                for (int ni = 0; ni < 4; ++ni)
                    acc[mi][ni] = __builtin_amdgcn_mfma_f32_16x16x32_bf16(
                        af[mi], bfv[ni], acc[mi][ni], 0, 0, 0);
        }
        __syncthreads();
        cur ^= 1;
    }

    #pragma unroll
    for (int ni = 0; ni < 4; ++ni) {
        const int col = (bn << 7) + wc + ni * 16 + fr;
        const float badd = hasBias ? bias[col] : 0.f;
        #pragma unroll
        for (int mi = 0; mi < 4; ++mi) {
            #pragma unroll
            for (int j = 0; j < 4; ++j) {
                const int row = (bm << 7) + wr + mi * 16 + fq * 4 + j;
                C[(size_t)row * N + col] = acc[mi][ni][j] + badd;
            }
        }
    }
}

// ---------- batched U = P * G^T for vis (single-pass bf16, K=N=256 padded) ----------
__global__ __launch_bounds__(256, 2)
void gemm_pg(const u16* __restrict__ P, const u16* __restrict__ G,
             float* __restrict__ U)
{
    const int v = blockIdx.z;
    const int bm = blockIdx.y, bn = blockIdx.x;
    const int tid = threadIdx.x;
    const int w = tid >> 6, lane = tid & 63;
    const int wr = (w >> 1) << 6, wc = (w & 1) << 6;
    const int fr = lane & 15, fq = lane >> 4;

    const u16* A2 = P + ((size_t)v << 19);
    const u16* B2 = G + ((size_t)v << 16);

    __shared__ u16 As[2][8192];
    __shared__ u16 Bs[2][8192];

    f32x4 acc[4][4];
    #pragma unroll
    for (int i = 0; i < 4; ++i)
        #pragma unroll
        for (int j = 0; j < 4; ++j) acc[i][j] = (f32x4){0.f, 0.f, 0.f, 0.f};

    const int swz = (fr & 7) << 4;
    const int aoff0 = ((wr + fr) << 7) >> 1;
    const int boff0 = ((wc + fr) << 7) >> 1;
    const int k0 = ((fq << 4) ^ swz) >> 1;
    const int k1 = ((64 + (fq << 4)) ^ swz) >> 1;
    const int c4 = w * 4;
    const int laneOff = c4 * 512 + lane * 8;

    int cur = 0;
    {
        const u16* ag = A2 + (((size_t)(bm * 4)) << 13) + laneOff;
        const u16* bg = B2 + (((size_t)(bn * 4)) << 13) + laneOff;
        #pragma unroll
        for (int i = 0; i < 4; ++i) {
            gload16(ag + i * 512, &As[0][(c4 + i) * 512]);
            gload16(bg + i * 512, &Bs[0][(c4 + i) * 512]);
        }
    }
    __syncthreads();

    for (int t = 0; t < 4; ++t) {
        if (t + 1 < 4) {
            const u16* ag = A2 + (((size_t)(bm * 4 + t + 1)) << 13) + laneOff;
            const u16* bg = B2 + (((size_t)(bn * 4 + t + 1)) << 13) + laneOff;
            int nb = cur ^ 1;
            #pragma unroll
            for (int i = 0; i < 4; ++i) {
                gload16(ag + i * 512, &As[nb][(c4 + i) * 512]);
                gload16(bg + i * 512, &Bs[nb][(c4 + i) * 512]);
            }
        }
        #pragma unroll
        for (int ks = 0; ks < 2; ++ks) {
            const int kk = ks ? k1 : k0;
            bf16x8 af[4], bfv[4];
            #pragma unroll
            for (int mi = 0; mi < 4; ++mi)
                af[mi] = *(const bf16x8*)&As[cur][aoff0 + mi * 1024 + kk];
            #pragma unroll
            for (int ni = 0; ni < 4; ++ni)
                bfv[ni] = *(const bf16x8*)&Bs[cur][boff0 + ni * 1024 + kk];
            #pragma unroll
            for (int mi = 0; mi < 4; ++mi)
                #pragma unroll
                for (int ni = 0; ni < 4; ++ni)
                    acc[mi][ni] = __builtin_amdgcn_mfma_f32_16x16x32_bf16(
                        af[mi], bfv[ni], acc[mi][ni], 0, 0, 0);
        }
        __syncthreads();
        cur ^= 1;
    }

    float* Uv = U + (size_t)v * MT * 196;
    #pragma unroll
    for (int ni = 0; ni < 4; ++ni) {
        const int col = (bn << 7) + wc + ni * 16 + fr;
        if (col < 196) {
            #pragma unroll
            for (int mi = 0; mi < 4; ++mi) {
                #pragma unroll
                for (int j = 0; j < 4; ++j) {
                    const int row = (bm << 7) + wr + mi * 16 + fq * 4 + j;
                    Uv[(size_t)row * 196 + col] = acc[mi][ni][j];
                }
            }
        }
    }
}

// ---------- Gram for TE (64x64 per t) -> bf16 swizzled zero-diag + fp32 diag ----------
__global__ __launch_bounds__(256)
void gram_text(const float* __restrict__ X, u16* __restrict__ Gtp,
               float* __restrict__ diagT)
{
    const int bat = blockIdx.z;
    const int tid = threadIdx.x;
    const int tx = tid & 15, ty = tid >> 4;
    __shared__ float Xa[32][68];
    const float* Xbase = X + (size_t)bat * 64 * DD;

    float acc[4][4];
    #pragma unroll
    for (int i = 0; i < 4; ++i)
        #pragma unroll
        for (int j = 0; j < 4; ++j) acc[i][j] = 0.f;

    for (int k0 = 0; k0 < DD; k0 += 32) {
        {
            int idx = tid;
            #pragma unroll
            for (int i = 0; i < 2; ++i) {
                int id2 = idx + 256 * i;
                int row = id2 >> 3;
                int kc  = (id2 & 7) << 2;
                float4 av = *(const float4*)(Xbase + (size_t)row * DD + k0 + kc);
                Xa[kc + 0][row] = av.x; Xa[kc + 1][row] = av.y;
                Xa[kc + 2][row] = av.z; Xa[kc + 3][row] = av.w;
            }
        }
        __syncthreads();
        #pragma unroll 8
        for (int kk = 0; kk < 32; ++kk) {
            float a[4], b[4];
            *(float4*)a = *(const float4*)&Xa[kk][ty * 4];
            *(float4*)b = *(const float4*)&Xa[kk][tx * 4];
            #pragma unroll
            for (int i = 0; i < 4; ++i)
                #pragma unroll
                for (int j = 0; j < 4; ++j)
                    acc[i][j] = fmaf(a[i], b[j], acc[i][j]);
        }
        __syncthreads();
    }

    u16* Gv = Gtp + ((size_t)bat << 12);
    #pragma unroll
    for (int i = 0; i < 4; ++i) {
        const int row = ty * 4 + i;
        #pragma unroll
        for (int jj = 0; jj < 4; ++jj) {
            const int col = tx * 4 + jj;
            float val = acc[i][jj];
            Gv[row * 64 + ((((col >> 3) ^ (row & 7)) << 3) | (col & 7))] =
                (row != col) ? f2bf(val) : (u16)0;
            if (row == col) diagT[bat * 64 + row] = val;
        }
    }
}

// ---------- Gram for VE (196x196) -> bf16 tiled 256x256, zero diag + fp32 diag ----------
__global__ __launch_bounds__(256)
void gram_vis(const float* __restrict__ X, u16* __restrict__ Gp,
              float* __restrict__ diagF)
{
    const int bat = blockIdx.z;
    const int it = blockIdx.y, jt = blockIdx.x;
    const int tid = threadIdx.x;
    const int tx = tid & 15, ty = tid >> 4;
    __shared__ float Xa[32][68];
    __shared__ float Xb[32][68];
    const float* Xbase = X + (size_t)bat * 196 * DD;

    float acc[4][4];
    #pragma unroll
    for (int i = 0; i < 4; ++i)
        #pragma unroll
        for (int j = 0; j < 4; ++j) acc[i][j] = 0.f;

    for (int k0 = 0; k0 < DD; k0 += 32) {
        #pragma unroll
        for (int i = 0; i < 2; ++i) {
            int idx = tid + 256 * i;
            int row = idx >> 3;
            int kc  = (idx & 7) << 2;
            int ra = it * 64 + row; ra = (ra < 196) ? ra : 195;
            int rb = jt * 64 + row; rb = (rb < 196) ? rb : 195;
            float4 av = *(const float4*)(Xbase + (size_t)ra * DD + k0 + kc);
            Xa[kc + 0][row] = av.x; Xa[kc + 1][row] = av.y;
            Xa[kc + 2][row] = av.z; Xa[kc + 3][row] = av.w;
            float4 bv = *(const float4*)(Xbase + (size_t)rb * DD + k0 + kc);
            Xb[kc + 0][row] = bv.x; Xb[kc + 1][row] = bv.y;
            Xb[kc + 2][row] = bv.z; Xb[kc + 3][row] = bv.w;
        }
        __syncthreads();
        #pragma unroll 8
        for (int kk = 0; kk < 32; ++kk) {
            float a[4], b[4];
            *(float4*)a = *(const float4*)&Xa[kk][ty * 4];
            *(float4*)b = *(const float4*)&Xb[kk][tx * 4];
            #pragma unroll
            for (int i = 0; i < 4; ++i)
                #pragma unroll
                for (int j = 0; j < 4; ++j)
                    acc[i][j] = fmaf(a[i], b[j], acc[i][j]);
        }
        __syncthreads();
    }

    u16* Gv = Gp + ((size_t)bat << 16);
    #pragma unroll
    for (int i = 0; i < 4; ++i) {
        const int row = it * 64 + ty * 4 + i;
        #pragma unroll
        for (int jj = 0; jj < 4; ++jj) {
            const int col = jt * 64 + tx * 4 + jj;
            float val = acc[i][jj];
            u16 o = (row < 196 && col < 196 && row != col) ? f2bf(val) : (u16)0;
            Gv[tiled_chunk_off(row, col & ~7, 4) + (col & 7)] = o;
            if (row == col && row < 196) diagF[bat * 196 + row] = val;
        }
    }
}

// ---------- zero WT ----------
__global__ __launch_bounds__(256)
void zero_wt(float* __restrict__ WT)
{
    WT[blockIdx.x * 256 + threadIdx.x] = 0.f;
}

// ---------- fused att_text: softmax + MFMA U=P*G + norm + w-atomics ----------
__global__ __launch_bounds__(256, 2)
void text_fused(const float* __restrict__ S1, const u16* __restrict__ Gtp,
                const float* __restrict__ diagT, const int* __restrict__ mask,
                float* __restrict__ WT)
{
    const int rb = blockIdx.x;   // 0..48 (128-row blocks of 6272)
    const int t  = blockIdx.y;   // 0..31
    const int tid = threadIdx.x;
    const int w = tid >> 6, lane = tid & 63;
    const int fr = lane & 15, fq = lane >> 4;

    __shared__ float Sblk[128 * 64];       // 32 KB; reused as Ulds
    __shared__ u16   Ap[128 * 64];         // 16 KB (bf16 A-image, swizzled)
    __shared__ u16   Glds[64 * 64];        // 8 KB
    __shared__ float dsh[64];
    __shared__ float wacc[4][2][64];       // 2 KB

    // stage FULL 8KB G tile (2 x 4KB)
    gload16(Gtp + ((size_t)t << 12) + tid * 8,        &Glds[tid * 8]);
    gload16(Gtp + ((size_t)t << 12) + 2048 + tid * 8, &Glds[2048 + tid * 8]);
    if (tid < 64) dsh[tid] = diagT[t * 64 + tid];
    // stage S block
    {
        const float* sbase = S1 + (size_t)(rb * 128) * MT + t * 64;
        #pragma unroll
        for (int i = 0; i < 8; ++i) {
            int idx = tid + i * 256;
            int row = idx >> 4, c4 = (idx & 15) << 2;
            *(float4*)&Sblk[row * 64 + c4] = *(const float4*)(sbase + (size_t)row * MT + c4);
        }
    }
    wacc[w][0][lane] = 0.f; wacc[w][1][lane] = 0.f;
    const int mk = mask[t * 64 + lane];
    __syncthreads();

    // softmax per row -> Ap (swizzled bf16 A-image)
    for (int rr = w; rr < 128; rr += 4) {
        float s = Sblk[rr * 64 + lane];
        float logit = mk ? NEGF : fmaxf(s, 0.f) * TEMPF;
        float mx = logit;
        #pragma unroll
        for (int off = 32; off; off >>= 1) mx = fmaxf(mx, __shfl_xor(mx, off, 64));
        float p = __expf(logit - mx);
        float sum = p;
        #pragma unroll
        for (int off = 32; off; off >>= 1) sum += __shfl_xor(sum, off, 64);
        p /= sum;
        Ap[rr * 64 + ((((lane >> 3) ^ (rr & 7)) << 3) | (lane & 7))] = f2bf(p);
    }
    __syncthreads();

    // MFMA: U(128x64) = P(128x64) * G^T(64x64)
    const int wr = (w >> 1) << 6, wc = (w & 1) << 5;
    f32x4 acc[4][2];
    #pragma unroll
    for (int i = 0; i < 4; ++i) { acc[i][0] = (f32x4){0,0,0,0}; acc[i][1] = (f32x4){0,0,0,0}; }
    const int swz = (fr & 7) << 4;
    const int aoff0 = (wr + fr) * 64;
    const int boff0 = (wc + fr) * 64;
    const int k0 = ((fq << 4) ^ swz) >> 1;
    const int k1 = ((64 + (fq << 4)) ^ swz) >> 1;
    #pragma unroll
    for (int ks = 0; ks < 2; ++ks) {
        const int kk = ks ? k1 : k0;
        bf16x8 af[4], bfv[2];
        #pragma unroll
        for (int mi = 0; mi < 4; ++mi)
            af[mi] = *(const bf16x8*)&Ap[aoff0 + mi * 1024 + kk];
        #pragma unroll
        for (int ni = 0; ni < 2; ++ni)
            bfv[ni] = *(const bf16x8*)&Glds[boff0 + ni * 1024 + kk];
        #pragma unroll
        for (int mi = 0; mi < 4; ++mi)
            #pragma unroll
            for (int ni = 0; ni < 2; ++ni)
                acc[mi][ni] = __builtin_amdgcn_mfma_f32_16x16x32_bf16(
                    af[mi], bfv[ni], acc[mi][ni], 0, 0, 0);
    }
    // write U into Sblk (dead) — NOT Ap (still read in nsq phase)
    float* Ulds = Sblk;
    #pragma unroll
    for (int ni = 0; ni < 2; ++ni)
        #pragma unroll
        for (int mi = 0; mi < 4; ++mi)
            #pragma unroll
            for (int j = 0; j < 4; ++j)
                Ulds[(wr + mi * 16 + fq * 4 + j) * 64 + (wc + ni * 16 + fr)] = acc[mi][ni][j];
    __syncthreads();

    // per-row nsq -> inv -> accumulate w per v-slot
    const int vb = ((rb * 128) / 196 + 1) * 196;   // global row where v increments
    for (int rr = w; rr < 128; rr += 4) {
        int r = rb * 128 + rr;
        float p = bf2f(Ap[rr * 64 + ((((lane >> 3) ^ (rr & 7)) << 3) | (lane & 7))]);
        float u = Ulds[rr * 64 + lane];
        float nsq = p * (u + dsh[lane] * p);
        #pragma unroll
        for (int off = 32; off; off >>= 1) nsq += __shfl_xor(nsq, off, 64);
        float inv = 1.f / fmaxf(sqrtf(fmaxf(nsq, 0.f)), 1e-12f);
        int slot = (r >= vb) ? 1 : 0;
        wacc[w][slot][lane] += p * inv;
    }
    __syncthreads();
    if (tid < 128) {
        int slot = tid >> 6, m = tid & 63;
        int v = (rb * 128) / 196 + slot;
        if (v < 32) {
            float val = wacc[0][slot][m] + wacc[1][slot][m] + wacc[2][slot][m] + wacc[3][slot][m];
            atomicAdd(&WT[((size_t)t * 32 + v) * 64 + m], val);
        }
    }
}

// ---------- a[t][v][:] = w . TE_t ----------
__global__ __launch_bounds__(256)
void text_a(const float* __restrict__ WT, const float* __restrict__ TE,
            float* __restrict__ aacc)
{
    const int t = blockIdx.x, v = blockIdx.y;
    const int tid = threadIdx.x;
    __shared__ float wl[64];
    if (tid < 64) wl[tid] = WT[((size_t)t * 32 + v) * 64 + tid];
    __syncthreads();
    const int d = tid * 2;
    float a0 = 0.f, a1 = 0.f;
    const float* tb = TE + (size_t)(t * 64) * DD + d;
    for (int m = 0; m < 64; ++m) {
        float wm = wl[m];
        float2 te = *(const float2*)(tb + (size_t)m * DD);
        a0 = fmaf(wm, te.x, a0);
        a1 = fmaf(wm, te.y, a1);
    }
    *(float2*)(aacc + ((size_t)t * 32 + v) * DD + d) = make_float2(a0, a1);
}

// ---------- row-softmax of S2 per (row, v) -> P bf16 tiled, K-padded to 256 ----------
__global__ __launch_bounds__(256)
void softmax_vis(const float* __restrict__ S2, u16* __restrict__ P)
{
    const int row  = blockIdx.x;
    const int wave = threadIdx.x >> 6, lane = threadIdx.x & 63;
    const int v = blockIdx.y * 4 + wave;
    __shared__ float pl[4][256];

    const float* srow = S2 + (size_t)row * MV + v * 196;
    float l0 = fmaxf(srow[lane], 0.f) * TEMPF;
    float l1 = fmaxf(srow[lane + 64], 0.f) * TEMPF;
    float l2 = fmaxf(srow[lane + 128], 0.f) * TEMPF;
    float l3 = -3.0e38f;
    if (lane < 4) l3 = fmaxf(srow[lane + 192], 0.f) * TEMPF;
    float mx = fmaxf(fmaxf(l0, l1), fmaxf(l2, l3));
    #pragma unroll
    for (int off = 32; off; off >>= 1) mx = fmaxf(mx, __shfl_xor(mx, off, 64));
    float p0 = __expf(l0 - mx), p1 = __expf(l1 - mx), p2 = __expf(l2 - mx);
    float p3 = (lane < 4) ? __expf(l3 - mx) : 0.f;
    float sum = p0 + p1 + p2 + p3;
    #pragma unroll
    for (int off = 32; off; off >>= 1) sum += __shfl_xor(sum, off, 64);
    float rs = 1.f / sum;
    pl[wave][lane]       = p0 * rs;
    pl[wave][lane + 64]  = p1 * rs;
    pl[wave][lane + 128] = p2 * rs;
    if (lane < 4) pl[wave][lane + 192] = p3 * rs;
    else          pl[wave][lane + 192] = 0.f;
    __syncthreads();

    if (lane < 32) {
        union { u16 h[8]; uint4 u; } c;
        #pragma unroll
        for (int e = 0; e < 8; ++e) c.h[e] = f2bf(pl[wave][lane * 8 + e]);
        u16* Pv = P + ((size_t)v << 19);
        *(uint4*)&Pv[tiled_chunk_off(row, lane * 8, 4)] = c.u;
    }
}

// ---------- per-row: nsq = p.U + p^2.diag -> inv; accumulate w ----------
__global__ __launch_bounds__(256)
void vis_norm_w(const float* __restrict__ U, const u16* __restrict__ P,
                const float* __restrict__ diagF, const int* __restrict__ mask,
                float* __restrict__ Wbuf)
{
    const int t = blockIdx.x, v = blockIdx.y;
    const int wave = threadIdx.x >> 6, lane = threadIdx.x & 63;
    __shared__ float wacc[4][200];

    for (int j = lane; j < 200; j += 64) wacc[wave][j] = 0.f;
    __syncthreads();

    const u16* Pv = P + ((size_t)v << 19);
    const float* dF = diagF + v * 196;
    const float d0 = dF[lane], d1 = dF[lane + 64], d2 = dF[lane + 128];
    const float d3 = (lane < 4) ? dF[lane + 192] : 0.f;

    for (int m = wave; m < 64; m += 4) {
        const int row = t * 64 + m;
        const float* urow = U + ((size_t)v * MT + row) * 196;
        float p0 = bf2f(Pv[tiled_chunk_off(row, lane & ~7, 4) + (lane & 7)]);
        float p1 = bf2f(Pv[tiled_chunk_off(row, (lane + 64) & ~7, 4) + (lane & 7)]);
        float p2 = bf2f(Pv[tiled_chunk_off(row, (lane + 128) & ~7, 4) + (lane & 7)]);
        float p3 = (lane < 4) ? bf2f(Pv[tiled_chunk_off(row, (lane + 192) & ~7, 4) + (lane & 7)]) : 0.f;
        float u0 = urow[lane], u1 = urow[lane + 64], u2 = urow[lane + 128];
        float u3 = (lane < 4) ? urow[lane + 192] : 0.f;
        float nsq = p0 * (u0 + d0 * p0) + p1 * (u1 + d1 * p1)
                  + p2 * (u2 + d2 * p2) + p3 * (u3 + d3 * p3);
        #pragma unroll
        for (int off = 32; off; off >>= 1) nsq += __shfl_xor(nsq, off, 64);
        float inv = 1.f / fmaxf(sqrtf(fmaxf(nsq, 0.f)), 1e-12f);
        if (mask[row]) inv = 0.f;
        wacc[wave][lane]       += p0 * inv;
        wacc[wave][lane + 64]  += p1 * inv;
        wacc[wave][lane + 128] += p2 * inv;
        if (lane < 4) wacc[wave][lane + 192] += p3 * inv;
    }
    __syncthreads();
    const int tid = threadIdx.x;
    if (tid < 196)
        Wbuf[((size_t)v * 32 + t) * 196 + tid] =
            wacc[0][tid] + wacc[1][tid] + wacc[2][tid] + wacc[3][tid];
}

// ---------- b[v][t][:] = w . VE_v ----------
__global__ __launch_bounds__(512)
void vis_b(const float* __restrict__ Wbuf, const float* __restrict__ VE,
           float* __restrict__ bacc)
{
    const int t = blockIdx.x, v = blockIdx.y;
    const int tid = threadIdx.x;
    __shared__ float wl[196];
    if (tid < 196) wl[tid] = Wbuf[((size_t)v * 32 + t) * 196 + tid];
    __syncthreads();
    float a0 = 0.f, a1 = 0.f;
    const float* vb = VE + (size_t)v * 196 * DD + tid;
    for (int j = 0; j < 196; j += 2) {
        a0 = fmaf(wl[j],     vb[(size_t)j * DD],       a0);
        a1 = fmaf(wl[j + 1], vb[(size_t)(j + 1) * DD], a1);
    }
    bacc[((size_t)v * 32 + t) * DD + tid] = a0 + a1;
}

// ---------- final: out[t,v] = dot(a[t,v,:], b[v,t,:]) / 12544 ----------
__global__ __launch_bounds__(64)
void final_dot(const float* __restrict__ aacc, const float* __restrict__ bacc,
               float* __restrict__ out)
{
    const int t = blockIdx.x, v = blockIdx.y;
    const int lane = threadIdx.x;
    const float* ap = aacc + ((size_t)t * 32 + v) * DD + lane * 8;
    const float* bp = bacc + ((size_t)v * 32 + t) * DD + lane * 8;
    float4 a0 = *(const float4*)ap,       a1 = *(const float4*)(ap + 4);
    float4 b0 = *(const float4*)bp,       b1 = *(const float4*)(bp + 4);
    float acc = a0.x*b0.x + a0.y*b0.y + a0.z*b0.z + a0.w*b0.w
              + a1.x*b1.x + a1.y*b1.y + a1.z*b1.z + a1.w*b1.w;
    #pragma unroll
    for (int off = 32; off; off >>= 1) acc += __shfl_xor(acc, off, 64);
    if (lane == 0) out[(size_t)t * 32 + v] = acc * (1.f / 12544.f);
}

// ---------- launcher ----------
extern "C" void kernel_launch(void* const* d_in, const int* in_sizes, int n_in,
                              void* d_out, int out_size, void* d_ws, size_t ws_size,
                              hipStream_t stream)
{
    const float* VF   = (const float*)d_in[0];
    const float* TF   = (const float*)d_in[1];
    const int*   mask = (const int*)  d_in[2];
    const float* Wv   = (const float*)d_in[3];
    const float* bv   = (const float*)d_in[4];
    const float* Wt   = (const float*)d_in[5];
    const float* bt   = (const float*)d_in[6];
    const float* Wq   = (const float*)d_in[7];
    const float* Wk   = (const float*)d_in[8];
    float* out = (float*)d_out;

    float* ws = (float*)d_ws;
    size_t off = 0;
    float* R1 = ws + off; off += (size_t)MV * MT;                    // 12.85M
    float* R2 = ws + off; off += (size_t)MV * DD + (size_t)MT * DD;  // 4.26M
    float* R3 = ws + off; off += (size_t)MV * DD;
    float* R4 = ws + off; off += (size_t)MT * DD;
    float* R5 = ws + off; off += (size_t)MV * DD;
    float* R6 = ws + off; off += (size_t)MT * DD;
    float* VE  = ws + off; off += (size_t)MV * DD;
    float* TE  = ws + off; off += (size_t)MT * DD;
    float* GtR = ws + off; off += (size_t)32 * 64 * 64;              // 131072 fl
    float* GvR = ws + off; off += (size_t)32 * 196 * 196;            // Gp + diagF + WT
    float* Aac = ws + off; off += (size_t)32 * 32 * DD;
    float* Bac = ws + off; off += (size_t)32 * 32 * DD;

    u16* VF2 = (u16*)R1;
    u16* TF2 = (u16*)R2;
    u16* VN2 = (u16*)R3;  u16* Qv2 = (u16*)R3;
    u16* TN2 = (u16*)R4;  u16* Qt2 = (u16*)R4;
    u16* Wv2 = (u16*)R5;
    u16* Wt2 = Wv2 + (size_t)512 * 1536;
    u16* Wq2 = Wt2 + (size_t)512 * 1536;
    u16* Wk2 = Wq2 + (size_t)512 * 1024;
    u16* Kv2 = (u16*)R5;
    u16* Kt2 = (u16*)R6;
    float* Qv = R1;
    float* Qt = R1 + (size_t)MV * DD;
    float* Kv = R2;
    float* Kt = R2 + (size_t)MV * DD;
    float* S  = R1;
    float* U  = R1;
    u16*   P  = (u16*)R3;
    u16*   Gtp  = (u16*)GtR;
    // Gtp = 32 batches x 4096 u16 = 131072 u16 = 65536 floats.
    // diagT AFTER it (round-8 bug: was GtR+32768, inside Gtp -> corruption).
    float* diagT = GtR + 65536;                // 2048 fl; 65536+2048 <= 131072 OK
    u16*   Gp = (u16*)GvR;
    float* diagF = GvR + (size_t)32 * 256 * 256 / 2;
    float* WT    = diagF + 6272;
    float* Wbuf = R2;

    // phase 1: conversions to split-bf16 tiled form
    conv_split<<<(MV * 96 + 255) / 256, 256, 0, stream>>>(VF, VF2, MV, 768);
    conv_split<<<(MT * 96 + 255) / 256, 256, 0, stream>>>(TF, TF2, MT, 768);
    conv_split<<<(512 * 96 + 255) / 256, 256, 0, stream>>>(Wv, Wv2, 512, 768);
    conv_split<<<(512 * 96 + 255) / 256, 256, 0, stream>>>(Wt, Wt2, 512, 768);
    conv_split<<<(512 * 64 + 255) / 256, 256, 0, stream>>>(Wq, Wq2, 512, 512);
    conv_split<<<(512 * 64 + 255) / 256, 256, 0, stream>>>(Wk, Wk2, 512, 512);

    // phase 2: embeds (+bias), split precision
    gemm_split_nt<<<dim3(4, 49), 256, 0, stream>>>(VF2, Wv2, bv, VE, MV, 512, 768, 1, 1);
    gemm_split_nt<<<dim3(4, 16), 256, 0, stream>>>(TF2, Wt2, bt, TE, MT, 512, 768, 1, 1);

    // phase 3: rownorm->split + grams
    rownorm_conv<<<MV / 4, 256, 0, stream>>>(VE, VN2, MV);
    rownorm_conv<<<MT / 4, 256, 0, stream>>>(TE, TN2, MT);
    gram_text<<<dim3(1, 1, 32), 256, 0, stream>>>(TE, Gtp, diagT);
    gram_vis<<<dim3(4, 4, 32), 256, 0, stream>>>(VE, Gp, diagF);

    // phase 4: projections, split precision
    gemm_split_nt<<<dim3(4, 49), 256, 0, stream>>>(VN2, Wq2, nullptr, Qv, MV, 512, 512, 0, 1);
    gemm_split_nt<<<dim3(4, 49), 256, 0, stream>>>(VN2, Wk2, nullptr, Kv, MV, 512, 512, 0, 1);
    gemm_split_nt<<<dim3(4, 16), 256, 0, stream>>>(TN2, Wq2, nullptr, Qt, MT, 512, 512, 0, 1);
    gemm_split_nt<<<dim3(4, 16), 256, 0, stream>>>(TN2, Wk2, nullptr, Kt, MT, 512, 512, 0, 1);

    // phase 5: normalize + split-convert projections
    rownorm_conv<<<MV / 4, 256, 0, stream>>>(Qv, Qv2, MV);
    rownorm_conv<<<MV / 4, 256, 0, stream>>>(Kv, Kv2, MV);
    rownorm_conv<<<MT / 4, 256, 0, stream>>>(Qt, Qt2, MT);
    rownorm_conv<<<MT / 4, 256, 0, stream>>>(Kt, Kt2, MT);

    // phase 6: S1 = Qv1*Kt1^T (single-pass bf16) -> fused text path
    gemm_split_nt<<<dim3(16, 49), 256, 0, stream>>>(Qv2, Kt2, nullptr, S, MV, MT, 512, 0, 0);
    zero_wt<<<256, 256, 0, stream>>>(WT);
    text_fused<<<dim3(49, 32), 256, 0, stream>>>(S, Gtp, diagT, mask, WT);
    text_a<<<dim3(32, 32), 256, 0, stream>>>(WT, TE, Aac);

    // phase 7: S2 = Qt1*Kv1^T (single-pass) -> vis path
    gemm_split_nt<<<dim3(49, 16), 256, 0, stream>>>(Qt2, Kv2, nullptr, S, MT, MV, 512, 0, 0);
    softmax_vis<<<dim3(MT, 8), 256, 0, stream>>>(S, P);
    gemm_pg<<<dim3(2, 16, 32), 256, 0, stream>>>(P, Gp, U);
    vis_norm_w<<<dim3(32, 32), 256, 0, stream>>>(U, P, diagF, mask, Wbuf);
    vis_b<<<dim3(32, 32), 512, 0, stream>>>(Wbuf, VE, Bac);

    final_dot<<<dim3(32, 32), 64, 0, stream>>>(Aac, Bac, out);
}

// Round 10
// 595.464 us; speedup vs baseline: 2.6154x; 1.1093x over previous
//
#include <hip/hip_runtime.h>
#include <math.h>

#define BV 32
#define LV 196
#define DV 768
#define BT 32
#define LT 64
#define DD 512
#define MV (BV*LV)   /* 6272 */
#define MT (BT*LT)   /* 2048 */
#define TEMPF 20.0f
#define NEGF  -1.0e9f

typedef unsigned short u16;
typedef unsigned int   u32;
typedef short bf16x8 __attribute__((ext_vector_type(8)));
typedef float f32x4  __attribute__((ext_vector_type(4)));

// ---------- helpers ----------
__device__ __forceinline__ u16 f2bf(float f) {
    u32 u = __float_as_uint(f);
    u32 r = u + 0x7fffu + ((u >> 16) & 1u);
    return (u16)(r >> 16);
}
__device__ __forceinline__ float bf2f(u16 h) { return __uint_as_float(((u32)h) << 16); }

// Tiled-swizzled bf16 layout: matrix stored as 128x64 tiles (8192 ushorts).
// Element (row, ke): byte row*128 + (((ke>>3)^(row&7))<<4) + (ke&7)*2
__device__ __forceinline__ size_t tiled_chunk_off(int m, int kk, int KB2) {
    int rowBlk = m >> 7, row = m & 127;
    int kBlk = kk >> 6, ke = kk & 63;
    return ((size_t)(rowBlk * KB2 + kBlk) << 13) + row * 64 + ((((ke >> 3) ^ (row & 7)) << 4) >> 1);
}

// ---------- conv: X fp32 [M][K] -> X2 bf16 tiled [hi | lo] (K2 = 2K) ----------
__global__ __launch_bounds__(256)
void conv_split(const float* __restrict__ X, u16* __restrict__ X2, int M, int K)
{
    int gid = blockIdx.x * 256 + threadIdx.x;
    int perRow = K >> 3;
    if (gid >= M * perRow) return;
    int m = gid / perRow, k8 = (gid - m * perRow) << 3;
    const float* xp = X + (size_t)m * K + k8;
    float x[8];
    *(float4*)&x[0] = *(const float4*)xp;
    *(float4*)&x[4] = *(const float4*)(xp + 4);
    union { u16 h[8]; uint4 v; } hi, lo;
    #pragma unroll
    for (int e = 0; e < 8; ++e) {
        hi.h[e] = f2bf(x[e]);
        lo.h[e] = f2bf(x[e] - bf2f(hi.h[e]));
    }
    int KB2 = K >> 5;
    *(uint4*)&X2[tiled_chunk_off(m, k8, KB2)]     = hi.v;
    *(uint4*)&X2[tiled_chunk_off(m, K + k8, KB2)] = lo.v;
}

// ---------- fused rownorm + split conv (rows of 512) ----------
__global__ __launch_bounds__(256)
void rownorm_conv(const float* __restrict__ X, u16* __restrict__ X2, int M)
{
    const int row  = blockIdx.x * 4 + (threadIdx.x >> 6);
    const int lane = threadIdx.x & 63;
    const float* ip = X + (size_t)row * DD + lane * 8;
    float x[8];
    *(float4*)&x[0] = *(const float4*)ip;
    *(float4*)&x[4] = *(const float4*)(ip + 4);
    float ss = 0.f;
    #pragma unroll
    for (int e = 0; e < 8; ++e) ss += x[e] * x[e];
    #pragma unroll
    for (int off = 32; off; off >>= 1) ss += __shfl_xor(ss, off, 64);
    const float inv = 1.f / fmaxf(sqrtf(ss), 1e-12f);
    union { u16 h[8]; uint4 v; } hi, lo;
    #pragma unroll
    for (int e = 0; e < 8; ++e) {
        float xv = x[e] * inv;
        hi.h[e] = f2bf(xv);
        lo.h[e] = f2bf(xv - bf2f(hi.h[e]));
    }
    const int k8 = lane * 8, KB2 = 16;  // K=512
    *(uint4*)&X2[tiled_chunk_off(row, k8, KB2)]       = hi.v;
    *(uint4*)&X2[tiled_chunk_off(row, DD + k8, KB2)]  = lo.v;
}

// ---------- bf16 MFMA GEMM NT: C[M,N] = A*B^T (+bias) ----------
// split=1: 3 passes (Ah*Bh + Ah*Bl + Al*Bh). split=0: single pass (hi only).
__device__ __forceinline__ void gload16(const u16* g, u16* l) {
    __builtin_amdgcn_global_load_lds((const __attribute__((address_space(1))) u32*)g,
                                     (__attribute__((address_space(3))) u32*)l, 16, 0, 0);
}

__global__ __launch_bounds__(256, 2)
void gemm_split_nt(const u16* __restrict__ A2, const u16* __restrict__ B2,
                   const float* __restrict__ bias, float* __restrict__ C,
                   int M, int N, int K, int hasBias, int split)
{
    const int KB  = K >> 6;
    const int KB2 = KB * 2;
    const int bm = blockIdx.y, bn = blockIdx.x;
    const int tid = threadIdx.x;
    const int w = tid >> 6, lane = tid & 63;
    const int wr = (w >> 1) << 6, wc = (w & 1) << 6;
    const int fr = lane & 15, fq = lane >> 4;

    __shared__ u16 As[2][8192];
    __shared__ u16 Bs[2][8192];

    f32x4 acc[4][4];
    #pragma unroll
    for (int i = 0; i < 4; ++i)
        #pragma unroll
        for (int j = 0; j < 4; ++j) acc[i][j] = (f32x4){0.f, 0.f, 0.f, 0.f};

    const int swz = (fr & 7) << 4;
    const int aoff0 = ((wr + fr) << 7) >> 1;
    const int boff0 = ((wc + fr) << 7) >> 1;
    const int k0 = ((fq << 4) ^ swz) >> 1;
    const int k1 = ((64 + (fq << 4)) ^ swz) >> 1;

    const int c4 = w * 4;
    const int laneOff = c4 * 512 + lane * 8;

    const int T = split ? 3 * KB : KB;
    int cur = 0;

    {
        const u16* ag = A2 + (((size_t)(bm * KB2)) << 13) + laneOff;
        const u16* bg = B2 + (((size_t)(bn * KB2)) << 13) + laneOff;
        #pragma unroll
        for (int i = 0; i < 4; ++i) {
            gload16(ag + i * 512, &As[0][(c4 + i) * 512]);
            gload16(bg + i * 512, &Bs[0][(c4 + i) * 512]);
        }
    }
    __syncthreads();

    for (int t = 0; t < T; ++t) {
        if (t + 1 < T) {
            int tn = t + 1, ab, bb;
            if (tn < KB)           { ab = tn;          bb = tn; }
            else if (tn < 2 * KB)  { ab = tn - KB;     bb = tn; }
            else                   { ab = tn - KB;     bb = tn - 2 * KB; }
            const u16* ag = A2 + (((size_t)(bm * KB2 + ab)) << 13) + laneOff;
            const u16* bg = B2 + (((size_t)(bn * KB2 + bb)) << 13) + laneOff;
            int nb = cur ^ 1;
            #pragma unroll
            for (int i = 0; i < 4; ++i) {
                gload16(ag + i * 512, &As[nb][(c4 + i) * 512]);
                gload16(bg + i * 512, &Bs[nb][(c4 + i) * 512]);
            }
        }
        #pragma unroll
        for (int ks = 0; ks < 2; ++ks) {
            const int kk = ks ? k1 : k0;
            bf16x8 af[4], bfv[4];
            #pragma unroll
            for (int mi = 0; mi < 4; ++mi)
                af[mi] = *(const bf16x8*)&As[cur][aoff0 + mi * 1024 + kk];
            #pragma unroll
            for (int ni = 0; ni < 4; ++ni)
                bfv[ni] = *(const bf16x8*)&Bs[cur][boff0 + ni * 1024 + kk];
            #pragma unroll
            for (int mi = 0; mi < 4; ++mi)
                #pragma unroll
                for (int ni = 0; ni < 4; ++ni)
                    acc[mi][ni] = __builtin_amdgcn_mfma_f32_16x16x32_bf16(
                        af[mi], bfv[ni], acc[mi][ni], 0, 0, 0);
        }
        __syncthreads();
        cur ^= 1;
    }

    #pragma unroll
    for (int ni = 0; ni < 4; ++ni) {
        const int col = (bn << 7) + wc + ni * 16 + fr;
        const float badd = hasBias ? bias[col] : 0.f;
        #pragma unroll
        for (int mi = 0; mi < 4; ++mi) {
            #pragma unroll
            for (int j = 0; j < 4; ++j) {
                const int row = (bm << 7) + wr + mi * 16 + fq * 4 + j;
                C[(size_t)row * N + col] = acc[mi][ni][j] + badd;
            }
        }
    }
}

// ---------- batched U = E * G^T for vis (single-pass bf16, K=N=256 padded) ----------
__global__ __launch_bounds__(256, 2)
void gemm_pg(const u16* __restrict__ P, const u16* __restrict__ G,
             float* __restrict__ U)
{
    const int v = blockIdx.z;
    const int bm = blockIdx.y, bn = blockIdx.x;
    const int tid = threadIdx.x;
    const int w = tid >> 6, lane = tid & 63;
    const int wr = (w >> 1) << 6, wc = (w & 1) << 6;
    const int fr = lane & 15, fq = lane >> 4;

    const u16* A2 = P + ((size_t)v << 19);
    const u16* B2 = G + ((size_t)v << 16);

    __shared__ u16 As[2][8192];
    __shared__ u16 Bs[2][8192];

    f32x4 acc[4][4];
    #pragma unroll
    for (int i = 0; i < 4; ++i)
        #pragma unroll
        for (int j = 0; j < 4; ++j) acc[i][j] = (f32x4){0.f, 0.f, 0.f, 0.f};

    const int swz = (fr & 7) << 4;
    const int aoff0 = ((wr + fr) << 7) >> 1;
    const int boff0 = ((wc + fr) << 7) >> 1;
    const int k0 = ((fq << 4) ^ swz) >> 1;
    const int k1 = ((64 + (fq << 4)) ^ swz) >> 1;
    const int c4 = w * 4;
    const int laneOff = c4 * 512 + lane * 8;

    int cur = 0;
    {
        const u16* ag = A2 + (((size_t)(bm * 4)) << 13) + laneOff;
        const u16* bg = B2 + (((size_t)(bn * 4)) << 13) + laneOff;
        #pragma unroll
        for (int i = 0; i < 4; ++i) {
            gload16(ag + i * 512, &As[0][(c4 + i) * 512]);
            gload16(bg + i * 512, &Bs[0][(c4 + i) * 512]);
        }
    }
    __syncthreads();

    for (int t = 0; t < 4; ++t) {
        if (t + 1 < 4) {
            const u16* ag = A2 + (((size_t)(bm * 4 + t + 1)) << 13) + laneOff;
            const u16* bg = B2 + (((size_t)(bn * 4 + t + 1)) << 13) + laneOff;
            int nb = cur ^ 1;
            #pragma unroll
            for (int i = 0; i < 4; ++i) {
                gload16(ag + i * 512, &As[nb][(c4 + i) * 512]);
                gload16(bg + i * 512, &Bs[nb][(c4 + i) * 512]);
            }
        }
        #pragma unroll
        for (int ks = 0; ks < 2; ++ks) {
            const int kk = ks ? k1 : k0;
            bf16x8 af[4], bfv[4];
            #pragma unroll
            for (int mi = 0; mi < 4; ++mi)
                af[mi] = *(const bf16x8*)&As[cur][aoff0 + mi * 1024 + kk];
            #pragma unroll
            for (int ni = 0; ni < 4; ++ni)
                bfv[ni] = *(const bf16x8*)&Bs[cur][boff0 + ni * 1024 + kk];
            #pragma unroll
            for (int mi = 0; mi < 4; ++mi)
                #pragma unroll
                for (int ni = 0; ni < 4; ++ni)
                    acc[mi][ni] = __builtin_amdgcn_mfma_f32_16x16x32_bf16(
                        af[mi], bfv[ni], acc[mi][ni], 0, 0, 0);
        }
        __syncthreads();
        cur ^= 1;
    }

    float* Uv = U + (size_t)v * MT * 196;
    #pragma unroll
    for (int ni = 0; ni < 4; ++ni) {
        const int col = (bn << 7) + wc + ni * 16 + fr;
        if (col < 196) {
            #pragma unroll
            for (int mi = 0; mi < 4; ++mi) {
                #pragma unroll
                for (int j = 0; j < 4; ++j) {
                    const int row = (bm << 7) + wr + mi * 16 + fq * 4 + j;
                    Uv[(size_t)row * 196 + col] = acc[mi][ni][j];
                }
            }
        }
    }
}

// ---------- Gram for TE (64x64 per t) -> bf16 swizzled zero-diag + fp32 diag ----------
__global__ __launch_bounds__(256)
void gram_text(const float* __restrict__ X, u16* __restrict__ Gtp,
               float* __restrict__ diagT)
{
    const int bat = blockIdx.z;
    const int tid = threadIdx.x;
    const int tx = tid & 15, ty = tid >> 4;
    __shared__ float Xa[32][68];
    const float* Xbase = X + (size_t)bat * 64 * DD;

    float acc[4][4];
    #pragma unroll
    for (int i = 0; i < 4; ++i)
        #pragma unroll
        for (int j = 0; j < 4; ++j) acc[i][j] = 0.f;

    for (int k0 = 0; k0 < DD; k0 += 32) {
        {
            int idx = tid;
            #pragma unroll
            for (int i = 0; i < 2; ++i) {
                int id2 = idx + 256 * i;
                int row = id2 >> 3;
                int kc  = (id2 & 7) << 2;
                float4 av = *(const float4*)(Xbase + (size_t)row * DD + k0 + kc);
                Xa[kc + 0][row] = av.x; Xa[kc + 1][row] = av.y;
                Xa[kc + 2][row] = av.z; Xa[kc + 3][row] = av.w;
            }
        }
        __syncthreads();
        #pragma unroll 8
        for (int kk = 0; kk < 32; ++kk) {
            float a[4], b[4];
            *(float4*)a = *(const float4*)&Xa[kk][ty * 4];
            *(float4*)b = *(const float4*)&Xa[kk][tx * 4];
            #pragma unroll
            for (int i = 0; i < 4; ++i)
                #pragma unroll
                for (int j = 0; j < 4; ++j)
                    acc[i][j] = fmaf(a[i], b[j], acc[i][j]);
        }
        __syncthreads();
    }

    u16* Gv = Gtp + ((size_t)bat << 12);
    #pragma unroll
    for (int i = 0; i < 4; ++i) {
        const int row = ty * 4 + i;
        #pragma unroll
        for (int jj = 0; jj < 4; ++jj) {
            const int col = tx * 4 + jj;
            float val = acc[i][jj];
            Gv[row * 64 + ((((col >> 3) ^ (row & 7)) << 3) | (col & 7))] =
                (row != col) ? f2bf(val) : (u16)0;
            if (row == col) diagT[bat * 64 + row] = val;
        }
    }
}

// ---------- Gram for VE (196x196) -> bf16 tiled 256x256, zero diag + fp32 diag ----------
__global__ __launch_bounds__(256)
void gram_vis(const float* __restrict__ X, u16* __restrict__ Gp,
              float* __restrict__ diagF)
{
    const int bat = blockIdx.z;
    const int it = blockIdx.y, jt = blockIdx.x;
    const int tid = threadIdx.x;
    const int tx = tid & 15, ty = tid >> 4;
    __shared__ float Xa[32][68];
    __shared__ float Xb[32][68];
    const float* Xbase = X + (size_t)bat * 196 * DD;

    float acc[4][4];
    #pragma unroll
    for (int i = 0; i < 4; ++i)
        #pragma unroll
        for (int j = 0; j < 4; ++j) acc[i][j] = 0.f;

    for (int k0 = 0; k0 < DD; k0 += 32) {
        #pragma unroll
        for (int i = 0; i < 2; ++i) {
            int idx = tid + 256 * i;
            int row = idx >> 3;
            int kc  = (idx & 7) << 2;
            int ra = it * 64 + row; ra = (ra < 196) ? ra : 195;
            int rb = jt * 64 + row; rb = (rb < 196) ? rb : 195;
            float4 av = *(const float4*)(Xbase + (size_t)ra * DD + k0 + kc);
            Xa[kc + 0][row] = av.x; Xa[kc + 1][row] = av.y;
            Xa[kc + 2][row] = av.z; Xa[kc + 3][row] = av.w;
            float4 bv = *(const float4*)(Xbase + (size_t)rb * DD + k0 + kc);
            Xb[kc + 0][row] = bv.x; Xb[kc + 1][row] = bv.y;
            Xb[kc + 2][row] = bv.z; Xb[kc + 3][row] = bv.w;
        }
        __syncthreads();
        #pragma unroll 8
        for (int kk = 0; kk < 32; ++kk) {
            float a[4], b[4];
            *(float4*)a = *(const float4*)&Xa[kk][ty * 4];
            *(float4*)b = *(const float4*)&Xb[kk][tx * 4];
            #pragma unroll
            for (int i = 0; i < 4; ++i)
                #pragma unroll
                for (int j = 0; j < 4; ++j)
                    acc[i][j] = fmaf(a[i], b[j], acc[i][j]);
        }
        __syncthreads();
    }

    u16* Gv = Gp + ((size_t)bat << 16);
    #pragma unroll
    for (int i = 0; i < 4; ++i) {
        const int row = it * 64 + ty * 4 + i;
        #pragma unroll
        for (int jj = 0; jj < 4; ++jj) {
            const int col = jt * 64 + tx * 4 + jj;
            float val = acc[i][jj];
            u16 o = (row < 196 && col < 196 && row != col) ? f2bf(val) : (u16)0;
            Gv[tiled_chunk_off(row, col & ~7, 4) + (col & 7)] = o;
            if (row == col && row < 196) diagF[bat * 196 + row] = val;
        }
    }
}

// ---------- zero WT ----------
__global__ __launch_bounds__(256)
void zero_wt(float* __restrict__ WT)
{
    WT[blockIdx.x * 256 + threadIdx.x] = 0.f;
}

// ---------- fused att_text v2: E=exp (no reductions) + MFMA U=E*G + nsq + w-atomics ----------
// softmax sum cancels: w += e/sqrt(e^T G e), e = exp(relu(s)*20) (masked->0).
// logits <= 20 (unit q,k) so no max subtraction needed.
__global__ __launch_bounds__(256, 4)
void text_fused(const float* __restrict__ S1, const u16* __restrict__ Gtp,
                const float* __restrict__ diagT, const int* __restrict__ mask,
                float* __restrict__ WT)
{
    const int rb = blockIdx.x;   // 0..97 (64-row blocks of 6272)
    const int t  = blockIdx.y;   // 0..31
    const int tid = threadIdx.x;
    const int w = tid >> 6, lane = tid & 63;
    const int fr = lane & 15, fq = lane >> 4;

    __shared__ u16   Ap[64 * 64];          // 8 KB (bf16 E-image, swizzled)
    __shared__ u16   Glds[64 * 64];        // 8 KB
    __shared__ float Ulds[64 * 64];        // 16 KB
    __shared__ float dsh[64];
    __shared__ float wacc[4][2][64];       // 2 KB

    // stage full 8KB G tile
    gload16(Gtp + ((size_t)t << 12) + tid * 8,        &Glds[tid * 8]);
    gload16(Gtp + ((size_t)t << 12) + 2048 + tid * 8, &Glds[2048 + tid * 8]);
    if (tid < 64) dsh[tid] = diagT[t * 64 + tid];
    wacc[w][0][lane] = 0.f; wacc[w][1][lane] = 0.f;
    const int mk = mask[t * 64 + lane];
    const int r0 = rb * 64;

    // exp phase: elementwise, direct global read, NO reductions
    for (int rr = w; rr < 64; rr += 4) {
        float s = S1[(size_t)(r0 + rr) * MT + t * 64 + lane];
        float e = mk ? 0.f : __expf(fmaxf(s, 0.f) * TEMPF);
        Ap[rr * 64 + ((((lane >> 3) ^ (rr & 7)) << 3) | (lane & 7))] = f2bf(e);
    }
    __syncthreads();

    // MFMA: U(64x64) = E(64x64) * G^T(64x64); wave w owns rows w*16..w*16+15
    const int wr = w << 4;
    f32x4 acc[4];
    #pragma unroll
    for (int i = 0; i < 4; ++i) acc[i] = (f32x4){0.f, 0.f, 0.f, 0.f};
    const int swz = (fr & 7) << 4;
    const int aoff0 = (wr + fr) * 64;
    const int k0 = ((fq << 4) ^ swz) >> 1;
    const int k1 = ((64 + (fq << 4)) ^ swz) >> 1;
    #pragma unroll
    for (int ks = 0; ks < 2; ++ks) {
        const int kk = ks ? k1 : k0;
        bf16x8 af = *(const bf16x8*)&Ap[aoff0 + kk];
        #pragma unroll
        for (int ni = 0; ni < 4; ++ni) {
            bf16x8 bfv = *(const bf16x8*)&Glds[(ni * 16 + fr) * 64 + kk];
            acc[ni] = __builtin_amdgcn_mfma_f32_16x16x32_bf16(af, bfv, acc[ni], 0, 0, 0);
        }
    }
    #pragma unroll
    for (int ni = 0; ni < 4; ++ni)
        #pragma unroll
        for (int j = 0; j < 4; ++j)
            Ulds[(wr + fq * 4 + j) * 64 + ni * 16 + fr] = acc[ni][j];
    __syncthreads();

    // per-row nsq = e.(u + d*e) -> inv -> accumulate w per v-slot
    const int vb = (r0 / 196 + 1) * 196;   // global row where v increments
    for (int rr = w; rr < 64; rr += 4) {
        int r = r0 + rr;
        float e = bf2f(Ap[rr * 64 + ((((lane >> 3) ^ (rr & 7)) << 3) | (lane & 7))]);
        float u = Ulds[rr * 64 + lane];
        float nsq = e * (u + dsh[lane] * e);
        #pragma unroll
        for (int off = 32; off; off >>= 1) nsq += __shfl_xor(nsq, off, 64);
        float inv = 1.f / fmaxf(sqrtf(fmaxf(nsq, 0.f)), 1e-12f);
        int slot = (r >= vb) ? 1 : 0;
        wacc[w][slot][lane] += e * inv;
    }
    __syncthreads();
    if (tid < 128) {
        int slot = tid >> 6, m = tid & 63;
        int v = r0 / 196 + slot;
        if (v < 32) {
            float val = wacc[0][slot][m] + wacc[1][slot][m] + wacc[2][slot][m] + wacc[3][slot][m];
            atomicAdd(&WT[((size_t)t * 32 + v) * 64 + m], val);
        }
    }
}

// ---------- a[t][v][:] = w . TE_t ----------
__global__ __launch_bounds__(256)
void text_a(const float* __restrict__ WT, const float* __restrict__ TE,
            float* __restrict__ aacc)
{
    const int t = blockIdx.x, v = blockIdx.y;
    const int tid = threadIdx.x;
    __shared__ float wl[64];
    if (tid < 64) wl[tid] = WT[((size_t)t * 32 + v) * 64 + tid];
    __syncthreads();
    const int d = tid * 2;
    float a0 = 0.f, a1 = 0.f;
    const float* tb = TE + (size_t)(t * 64) * DD + d;
    for (int m = 0; m < 64; ++m) {
        float wm = wl[m];
        float2 te = *(const float2*)(tb + (size_t)m * DD);
        a0 = fmaf(wm, te.x, a0);
        a1 = fmaf(wm, te.y, a1);
    }
    *(float2*)(aacc + ((size_t)t * 32 + v) * DD + d) = make_float2(a0, a1);
}

// ---------- elementwise E = exp(relu(s)*20) of S2 -> bf16 tiled, K-padded to 256 ----------
// (softmax sum cancels in w = e/sqrt(e^T G e); no max needed since logits <= 20)
__global__ __launch_bounds__(256)
void exp_vis(const float* __restrict__ S2, u16* __restrict__ P)
{
    const int row  = blockIdx.x;
    const int wave = threadIdx.x >> 6, lane = threadIdx.x & 63;
    const int v = blockIdx.y * 4 + wave;
    __shared__ float pl[4][256];

    const float* srow = S2 + (size_t)row * MV + v * 196;
    pl[wave][lane]       = __expf(fmaxf(srow[lane], 0.f) * TEMPF);
    pl[wave][lane + 64]  = __expf(fmaxf(srow[lane + 64], 0.f) * TEMPF);
    pl[wave][lane + 128] = __expf(fmaxf(srow[lane + 128], 0.f) * TEMPF);
    pl[wave][lane + 192] = (lane < 4) ? __expf(fmaxf(srow[lane + 192], 0.f) * TEMPF) : 0.f;
    __syncthreads();

    if (lane < 32) {
        union { u16 h[8]; uint4 u; } c;
        #pragma unroll
        for (int e = 0; e < 8; ++e) c.h[e] = f2bf(pl[wave][lane * 8 + e]);
        u16* Pv = P + ((size_t)v << 19);
        *(uint4*)&Pv[tiled_chunk_off(row, lane * 8, 4)] = c.u;
    }
}

// ---------- per-row: nsq = e.U + e^2.diag -> inv; accumulate w ----------
__global__ __launch_bounds__(256)
void vis_norm_w(const float* __restrict__ U, const u16* __restrict__ P,
                const float* __restrict__ diagF, const int* __restrict__ mask,
                float* __restrict__ Wbuf)
{
    const int t = blockIdx.x, v = blockIdx.y;
    const int wave = threadIdx.x >> 6, lane = threadIdx.x & 63;
    __shared__ float wacc[4][200];

    for (int j = lane; j < 200; j += 64) wacc[wave][j] = 0.f;
    __syncthreads();

    const u16* Pv = P + ((size_t)v << 19);
    const float* dF = diagF + v * 196;
    const float d0 = dF[lane], d1 = dF[lane + 64], d2 = dF[lane + 128];
    const float d3 = (lane < 4) ? dF[lane + 192] : 0.f;

    for (int m = wave; m < 64; m += 4) {
        const int row = t * 64 + m;
        const float* urow = U + ((size_t)v * MT + row) * 196;
        float p0 = bf2f(Pv[tiled_chunk_off(row, lane & ~7, 4) + (lane & 7)]);
        float p1 = bf2f(Pv[tiled_chunk_off(row, (lane + 64) & ~7, 4) + (lane & 7)]);
        float p2 = bf2f(Pv[tiled_chunk_off(row, (lane + 128) & ~7, 4) + (lane & 7)]);
        float p3 = (lane < 4) ? bf2f(Pv[tiled_chunk_off(row, (lane + 192) & ~7, 4) + (lane & 7)]) : 0.f;
        float u0 = urow[lane], u1 = urow[lane + 64], u2 = urow[lane + 128];
        float u3 = (lane < 4) ? urow[lane + 192] : 0.f;
        float nsq = p0 * (u0 + d0 * p0) + p1 * (u1 + d1 * p1)
                  + p2 * (u2 + d2 * p2) + p3 * (u3 + d3 * p3);
        #pragma unroll
        for (int off = 32; off; off >>= 1) nsq += __shfl_xor(nsq, off, 64);
        float inv = 1.f / fmaxf(sqrtf(fmaxf(nsq, 0.f)), 1e-12f);
        if (mask[row]) inv = 0.f;
        wacc[wave][lane]       += p0 * inv;
        wacc[wave][lane + 64]  += p1 * inv;
        wacc[wave][lane + 128] += p2 * inv;
        if (lane < 4) wacc[wave][lane + 192] += p3 * inv;
    }
    __syncthreads();
    const int tid = threadIdx.x;
    if (tid < 196)
        Wbuf[((size_t)v * 32 + t) * 196 + tid] =
            wacc[0][tid] + wacc[1][tid] + wacc[2][tid] + wacc[3][tid];
}

// ---------- b[v][t][:] = w . VE_v ----------
__global__ __launch_bounds__(512)
void vis_b(const float* __restrict__ Wbuf, const float* __restrict__ VE,
           float* __restrict__ bacc)
{
    const int t = blockIdx.x, v = blockIdx.y;
    const int tid = threadIdx.x;
    __shared__ float wl[196];
    if (tid < 196) wl[tid] = Wbuf[((size_t)v * 32 + t) * 196 + tid];
    __syncthreads();
    float a0 = 0.f, a1 = 0.f;
    const float* vb = VE + (size_t)v * 196 * DD + tid;
    for (int j = 0; j < 196; j += 2) {
        a0 = fmaf(wl[j],     vb[(size_t)j * DD],       a0);
        a1 = fmaf(wl[j + 1], vb[(size_t)(j + 1) * DD], a1);
    }
    bacc[((size_t)v * 32 + t) * DD + tid] = a0 + a1;
}

// ---------- final: out[t,v] = dot(a[t,v,:], b[v,t,:]) / 12544 ----------
__global__ __launch_bounds__(64)
void final_dot(const float* __restrict__ aacc, const float* __restrict__ bacc,
               float* __restrict__ out)
{
    const int t = blockIdx.x, v = blockIdx.y;
    const int lane = threadIdx.x;
    const float* ap = aacc + ((size_t)t * 32 + v) * DD + lane * 8;
    const float* bp = bacc + ((size_t)v * 32 + t) * DD + lane * 8;
    float4 a0 = *(const float4*)ap,       a1 = *(const float4*)(ap + 4);
    float4 b0 = *(const float4*)bp,       b1 = *(const float4*)(bp + 4);
    float acc = a0.x*b0.x + a0.y*b0.y + a0.z*b0.z + a0.w*b0.w
              + a1.x*b1.x + a1.y*b1.y + a1.z*b1.z + a1.w*b1.w;
    #pragma unroll
    for (int off = 32; off; off >>= 1) acc += __shfl_xor(acc, off, 64);
    if (lane == 0) out[(size_t)t * 32 + v] = acc * (1.f / 12544.f);
}

// ---------- launcher ----------
extern "C" void kernel_launch(void* const* d_in, const int* in_sizes, int n_in,
                              void* d_out, int out_size, void* d_ws, size_t ws_size,
                              hipStream_t stream)
{
    const float* VF   = (const float*)d_in[0];
    const float* TF   = (const float*)d_in[1];
    const int*   mask = (const int*)  d_in[2];
    const float* Wv   = (const float*)d_in[3];
    const float* bv   = (const float*)d_in[4];
    const float* Wt   = (const float*)d_in[5];
    const float* bt   = (const float*)d_in[6];
    const float* Wq   = (const float*)d_in[7];
    const float* Wk   = (const float*)d_in[8];
    float* out = (float*)d_out;

    float* ws = (float*)d_ws;
    size_t off = 0;
    float* R1 = ws + off; off += (size_t)MV * MT;                    // 12.85M
    float* R2 = ws + off; off += (size_t)MV * DD + (size_t)MT * DD;  // 4.26M
    float* R3 = ws + off; off += (size_t)MV * DD;
    float* R4 = ws + off; off += (size_t)MT * DD;
    float* R5 = ws + off; off += (size_t)MV * DD;
    float* R6 = ws + off; off += (size_t)MT * DD;
    float* VE  = ws + off; off += (size_t)MV * DD;
    float* TE  = ws + off; off += (size_t)MT * DD;
    float* GtR = ws + off; off += (size_t)32 * 64 * 64;              // 131072 fl
    float* GvR = ws + off; off += (size_t)32 * 196 * 196;            // Gp + diagF + WT
    float* Aac = ws + off; off += (size_t)32 * 32 * DD;
    float* Bac = ws + off; off += (size_t)32 * 32 * DD;

    u16* VF2 = (u16*)R1;
    u16* TF2 = (u16*)R2;
    u16* VN2 = (u16*)R3;  u16* Qv2 = (u16*)R3;
    u16* TN2 = (u16*)R4;  u16* Qt2 = (u16*)R4;
    u16* Wv2 = (u16*)R5;
    u16* Wt2 = Wv2 + (size_t)512 * 1536;
    u16* Wq2 = Wt2 + (size_t)512 * 1536;
    u16* Wk2 = Wq2 + (size_t)512 * 1024;
    u16* Kv2 = (u16*)R5;
    u16* Kt2 = (u16*)R6;
    float* Qv = R1;
    float* Qt = R1 + (size_t)MV * DD;
    float* Kv = R2;
    float* Kt = R2 + (size_t)MV * DD;
    float* S  = R1;
    float* U  = R1;
    u16*   P  = (u16*)R3;
    u16*   Gtp  = (u16*)GtR;
    // Gtp = 32 x 4096 u16 = 131072 u16 = 65536 floats; diagT after it.
    float* diagT = GtR + 65536;
    u16*   Gp = (u16*)GvR;
    float* diagF = GvR + (size_t)32 * 256 * 256 / 2;
    float* WT    = diagF + 6272;
    float* Wbuf = R2;

    // phase 1: conversions to split-bf16 tiled form
    conv_split<<<(MV * 96 + 255) / 256, 256, 0, stream>>>(VF, VF2, MV, 768);
    conv_split<<<(MT * 96 + 255) / 256, 256, 0, stream>>>(TF, TF2, MT, 768);
    conv_split<<<(512 * 96 + 255) / 256, 256, 0, stream>>>(Wv, Wv2, 512, 768);
    conv_split<<<(512 * 96 + 255) / 256, 256, 0, stream>>>(Wt, Wt2, 512, 768);
    conv_split<<<(512 * 64 + 255) / 256, 256, 0, stream>>>(Wq, Wq2, 512, 512);
    conv_split<<<(512 * 64 + 255) / 256, 256, 0, stream>>>(Wk, Wk2, 512, 512);

    // phase 2: embeds (+bias), split precision
    gemm_split_nt<<<dim3(4, 49), 256, 0, stream>>>(VF2, Wv2, bv, VE, MV, 512, 768, 1, 1);
    gemm_split_nt<<<dim3(4, 16), 256, 0, stream>>>(TF2, Wt2, bt, TE, MT, 512, 768, 1, 1);

    // phase 3: rownorm->split + grams
    rownorm_conv<<<MV / 4, 256, 0, stream>>>(VE, VN2, MV);
    rownorm_conv<<<MT / 4, 256, 0, stream>>>(TE, TN2, MT);
    gram_text<<<dim3(1, 1, 32), 256, 0, stream>>>(TE, Gtp, diagT);
    gram_vis<<<dim3(4, 4, 32), 256, 0, stream>>>(VE, Gp, diagF);

    // phase 4: projections, split precision
    gemm_split_nt<<<dim3(4, 49), 256, 0, stream>>>(VN2, Wq2, nullptr, Qv, MV, 512, 512, 0, 1);
    gemm_split_nt<<<dim3(4, 49), 256, 0, stream>>>(VN2, Wk2, nullptr, Kv, MV, 512, 512, 0, 1);
    gemm_split_nt<<<dim3(4, 16), 256, 0, stream>>>(TN2, Wq2, nullptr, Qt, MT, 512, 512, 0, 1);
    gemm_split_nt<<<dim3(4, 16), 256, 0, stream>>>(TN2, Wk2, nullptr, Kt, MT, 512, 512, 0, 1);

    // phase 5: normalize + split-convert projections
    rownorm_conv<<<MV / 4, 256, 0, stream>>>(Qv, Qv2, MV);
    rownorm_conv<<<MV / 4, 256, 0, stream>>>(Kv, Kv2, MV);
    rownorm_conv<<<MT / 4, 256, 0, stream>>>(Qt, Qt2, MT);
    rownorm_conv<<<MT / 4, 256, 0, stream>>>(Kt, Kt2, MT);

    // phase 6: S1 = Qv1*Kt1^T (single-pass bf16) -> fused text path
    gemm_split_nt<<<dim3(16, 49), 256, 0, stream>>>(Qv2, Kt2, nullptr, S, MV, MT, 512, 0, 0);
    zero_wt<<<256, 256, 0, stream>>>(WT);
    text_fused<<<dim3(98, 32), 256, 0, stream>>>(S, Gtp, diagT, mask, WT);
    text_a<<<dim3(32, 32), 256, 0, stream>>>(WT, TE, Aac);

    // phase 7: S2 = Qt1*Kv1^T (single-pass) -> vis path
    gemm_split_nt<<<dim3(49, 16), 256, 0, stream>>>(Qt2, Kv2, nullptr, S, MT, MV, 512, 0, 0);
    exp_vis<<<dim3(MT, 8), 256, 0, stream>>>(S, P);
    gemm_pg<<<dim3(2, 16, 32), 256, 0, stream>>>(P, Gp, U);
    vis_norm_w<<<dim3(32, 32), 256, 0, stream>>>(U, P, diagF, mask, Wbuf);
    vis_b<<<dim3(32, 32), 512, 0, stream>>>(Wbuf, VE, Bac);

    final_dot<<<dim3(32, 32), 64, 0, stream>>>(Aac, Bac, out);
}